// Round 5
// baseline (244.701 us; speedup 1.0000x reference)
//
#include <hip/hip_runtime.h>
#include <math.h>

#define B_SZ 2
#define LSEQ 1024
#define D_INP 1024
#define D_MODEL 2048
#define D_STATE 16
#define D_DISCR 128
#define MROWS (B_SZ * LSEQ)
#define NCH 64
#define CH 16

typedef __bf16 bf16x8 __attribute__((ext_vector_type(8)));
typedef float f32x4 __attribute__((ext_vector_type(4)));
typedef unsigned short ushort8 __attribute__((ext_vector_type(8)));

__device__ __forceinline__ float siluf(float x) { return x / (1.f + expf(-x)); }
__device__ __forceinline__ float softplusf(float x) {
    return fmaxf(x, 0.f) + log1pf(expf(-fabsf(x)));
}
__device__ __forceinline__ unsigned short f2b(float f) {
    unsigned u = __builtin_bit_cast(unsigned, f);
    u = u + 0x7fffu + ((u >> 16) & 1u);
    return (unsigned short)(u >> 16);
}
__device__ __forceinline__ float b2f(unsigned short u) {
    return __builtin_bit_cast(float, ((unsigned)u) << 16);
}

// ---------------------------------------------------------------------------
__global__ __launch_bounds__(256) void cast_all(
    const float* __restrict__ seq, const float* __restrict__ w_in,
    const float* __restrict__ w_out, const float* __restrict__ w_B,
    const float* __restrict__ w_C, const float* __restrict__ w_D1,
    const float* __restrict__ w_D2,
    unsigned short* __restrict__ seq_b, unsigned short* __restrict__ win_b,
    unsigned short* __restrict__ wout_b, unsigned short* __restrict__ wbcd_b,
    unsigned short* __restrict__ wd2_b)
{
    int i = blockIdx.x * 256 + threadIdx.x;
    const float* src; unsigned short* dst; int off;
    if      (i < 262144)  { src = seq;  dst = seq_b;          off = i; }
    else if (i < 786432)  { src = w_in; dst = win_b;          off = i - 262144; }
    else if (i < 1048576) { src = w_out; dst = wout_b;        off = i - 786432; }
    else if (i < 1052672) { src = w_B;  dst = wbcd_b;         off = i - 1048576; }
    else if (i < 1056768) { src = w_C;  dst = wbcd_b + 32768; off = i - 1052672; }
    else if (i < 1089536) { src = w_D1; dst = wbcd_b + 65536; off = i - 1056768; }
    else if (i < 1122304) { src = w_D2; dst = wd2_b;          off = i - 1089536; }
    else return;
    const float4* p = (const float4*)(src + (size_t)off * 8);
    float4 a = p[0], b = p[1];
    ushort8 o = {f2b(a.x), f2b(a.y), f2b(a.z), f2b(a.w),
                 f2b(b.x), f2b(b.y), f2b(b.z), f2b(b.w)};
    *(ushort8*)(dst + (size_t)off * 8) = o;
}

// ---------------------------------------------------------------------------
// bf16 MFMA GEMM-NT — R12/R17 structure: 128xTN tile, BK=32, VGPR-staged
// single-slab prefetch double buffer, 1 barrier/K-iter, XOR-swizzled
// unpadded LDS (0 conflicts). R20: loop flavor is per-call-site.
//   UNR=true  (R19): pairwise-unrolled K-loop, COMPILE-TIME buffer index —
//     all LDS addresses loop-invariant. For long-K sites (gemm1 K=1024,
//     gemm6 K=512) where steady-state dominates.
//   UNR=false (R17): runtime-buf loop. For short-K sites (gemm3 K=256,
//     gemm4 K=128): R19's pinned unroll broke the compiler's short-pipeline
//     schedule — gemm4 41 -> 75.6 µs, MfmaUtil 0.5%, all pipes idle.
// Sweep history: 128x64 @4/CU = 41 µs (R12); 64x64 = 51 (R14); depth-2 =
// 54 (R11); gll = neutral (R13); padded = 71 (R6); 128x128 @2/CU = 85
// (R16 — barrier drain at 8 waves/CU); A-via-registers = 51.5 (R18 —
// exposed VMEM->MFMA dependency; LDS round-trip was free behind barrier).
// Block does K-chunk [z*K, z*K+K) -> Cbase + z*partStride.
// TN=128: 4 waves 2x2, 4x4 frags; TN=64: waves row-stacked, 2x4 frags.
// B rows past N read unguarded (must be allocated); masked at store.
// epi: 0 fp32 store; 2 softplus(bias[col]+acc) -> bf16 (Cbase as u16);
//      5 split both-bf16: col<2048 -> (u16*)Cbase, col>=2048 -> C2.
template <int TN, bool UNR>
__global__ __launch_bounds__(256) void gemm_db(
    const unsigned short* __restrict__ A, int lda,
    const unsigned short* __restrict__ B, int ldb,
    float* __restrict__ Cbase, int ldc, size_t partStride,
    int N, int K, const float* __restrict__ bias,
    unsigned short* __restrict__ C2, int epi)
{
    __shared__ unsigned short As[2][128 * 32];
    __shared__ unsigned short Bs[2][TN * 32];
    const int t = threadIdx.x;
    const int w = t >> 6, lane = t & 63;
    const int fr = lane & 15, fq = lane >> 4;
    const int row0 = blockIdx.y * 128, col0 = blockIdx.x * TN;
    const int kz = blockIdx.z * K;
    const int sr = t >> 2, sq = t & 3;
    const int sqz = sq ^ ((sr >> 1) & 3);      // swizzled store chunk
    const int qa = fq ^ ((fr >> 1) & 3);       // swizzled read chunk

    constexpr int NI = (TN == 128) ? 4 : 2;
    const int rbase = (TN == 128) ? (w >> 1) * 64 : w * 32;
    const int cbase = (TN == 128) ? (w & 1) * 64 : 0;

    const unsigned short* gA0 = A + (size_t)(row0 + sr) * lda + kz + sq * 8;
    const unsigned short* gA1 = gA0 + (size_t)64 * lda;
    const unsigned short* gB0 = B + (size_t)(col0 + sr) * ldb + kz + sq * 8;
    const unsigned short* gB1 = gB0 + (size_t)64 * ldb;

    f32x4 acc[NI][4];
#pragma unroll
    for (int i = 0; i < NI; i++)
#pragma unroll
        for (int j = 0; j < 4; j++) acc[i][j] = (f32x4){0.f, 0.f, 0.f, 0.f};

    // prologue: stage slab 0 into buffer 0
    ushort8 a0 = *(const ushort8*)gA0;
    ushort8 a1 = *(const ushort8*)gA1;
    ushort8 b0 = *(const ushort8*)gB0;
    ushort8 b1;
    if (TN == 128) b1 = *(const ushort8*)gB1;
    *(ushort8*)&As[0][sr * 32 + sqz * 8] = a0;
    *(ushort8*)&As[0][(64 + sr) * 32 + sqz * 8] = a1;
    *(ushort8*)&Bs[0][sr * 32 + sqz * 8] = b0;
    if (TN == 128) *(ushort8*)&Bs[0][(64 + sr) * 32 + sqz * 8] = b1;
    __syncthreads();

    if constexpr (UNR) {
        const int nhalf = K / 32;              // even at all UNR call sites
#pragma unroll 1
        for (int p = 0; p < nhalf; p += 2) {
#pragma unroll
            for (int h = 0; h < 2; ++h) {      // h = compile-time buffer idx
                const int k0 = (p + h) * 32;
                const bool more = (k0 + 32 < K);
                if (more) {                    // next-slab loads in flight
                    gA0 += 32; gA1 += 32; gB0 += 32; gB1 += 32;
                    a0 = *(const ushort8*)gA0;
                    a1 = *(const ushort8*)gA1;
                    b0 = *(const ushort8*)gB0;
                    if (TN == 128) b1 = *(const ushort8*)gB1;
                }
                bf16x8 af[NI], bfr[4];
#pragma unroll
                for (int i = 0; i < NI; i++) {
                    ushort8 u = *(const ushort8*)&As[h][(rbase + i * 16 + fr) * 32 + qa * 8];
                    af[i] = __builtin_bit_cast(bf16x8, u);
                }
#pragma unroll
                for (int j = 0; j < 4; j++) {
                    ushort8 u = *(const ushort8*)&Bs[h][(cbase + j * 16 + fr) * 32 + qa * 8];
                    bfr[j] = __builtin_bit_cast(bf16x8, u);
                }
#pragma unroll
                for (int i = 0; i < NI; i++)
#pragma unroll
                    for (int j = 0; j < 4; j++)
                        acc[i][j] = __builtin_amdgcn_mfma_f32_16x16x32_bf16(
                            af[i], bfr[j], acc[i][j], 0, 0, 0);
                if (more) {                    // vmcnt wait lands here, post-MFMA
                    *(ushort8*)&As[h ^ 1][sr * 32 + sqz * 8] = a0;
                    *(ushort8*)&As[h ^ 1][(64 + sr) * 32 + sqz * 8] = a1;
                    *(ushort8*)&Bs[h ^ 1][sr * 32 + sqz * 8] = b0;
                    if (TN == 128) *(ushort8*)&Bs[h ^ 1][(64 + sr) * 32 + sqz * 8] = b1;
                    __syncthreads();
                }
            }
        }
    } else {
        int buf = 0;
        for (int k0 = 0; k0 < K; k0 += 32) {
            const bool more = (k0 + 32 < K);
            if (more) {                        // next-slab loads in flight
                gA0 += 32; gA1 += 32; gB0 += 32; gB1 += 32;
                a0 = *(const ushort8*)gA0;
                a1 = *(const ushort8*)gA1;
                b0 = *(const ushort8*)gB0;
                if (TN == 128) b1 = *(const ushort8*)gB1;
            }
            bf16x8 af[NI], bfr[4];
#pragma unroll
            for (int i = 0; i < NI; i++) {
                ushort8 u = *(const ushort8*)&As[buf][(rbase + i * 16 + fr) * 32 + qa * 8];
                af[i] = __builtin_bit_cast(bf16x8, u);
            }
#pragma unroll
            for (int j = 0; j < 4; j++) {
                ushort8 u = *(const ushort8*)&Bs[buf][(cbase + j * 16 + fr) * 32 + qa * 8];
                bfr[j] = __builtin_bit_cast(bf16x8, u);
            }
#pragma unroll
            for (int i = 0; i < NI; i++)
#pragma unroll
                for (int j = 0; j < 4; j++)
                    acc[i][j] = __builtin_amdgcn_mfma_f32_16x16x32_bf16(
                        af[i], bfr[j], acc[i][j], 0, 0, 0);
            if (more) {
                int nb = buf ^ 1;              // vmcnt wait lands here, post-MFMA
                *(ushort8*)&As[nb][sr * 32 + sqz * 8] = a0;
                *(ushort8*)&As[nb][(64 + sr) * 32 + sqz * 8] = a1;
                *(ushort8*)&Bs[nb][sr * 32 + sqz * 8] = b0;
                if (TN == 128) *(ushort8*)&Bs[nb][(64 + sr) * 32 + sqz * 8] = b1;
                __syncthreads();
                buf = nb;
            }
        }
    }

    float* C = Cbase + (size_t)blockIdx.z * partStride;
#pragma unroll
    for (int i = 0; i < NI; i++) {
#pragma unroll
        for (int r = 0; r < 4; r++) {
            int row = row0 + rbase + i * 16 + fq * 4 + r;
#pragma unroll
            for (int j = 0; j < 4; j++) {   // j-inner: contiguous write runs
                int col = col0 + cbase + j * 16 + fr;
                if (col >= N) continue;
                float v = acc[i][j][r];
                if (epi == 0) C[(size_t)row * ldc + col] = v;
                else if (epi == 2)
                    ((unsigned short*)Cbase)[(size_t)row * ldc + col] =
                        f2b(softplusf(bias[col] + v));
                else {
                    unsigned short v16 = f2b(v);
                    if (col < 2048) ((unsigned short*)Cbase)[(size_t)row * 2048 + col] = v16;
                    else C2[(size_t)row * 2048 + col - 2048] = v16;
                }
            }
        }
    }
}

// ---------------------------------------------------------------------------
__global__ __launch_bounds__(256) void bcd_reduce(
    const float* __restrict__ part, unsigned short* __restrict__ bcdB,
    float* __restrict__ bc32)
{
    int t = blockIdx.x * 256 + threadIdx.x;
    if (t >= 327680) return;
    float s = 0.f;
#pragma unroll
    for (int z = 0; z < 8; z++) s += part[(size_t)z * 327680 + t];
    bcdB[t] = f2b(s);
    int col = t % 160;
    if (col < 32) bc32[(size_t)(t / 160) * 32 + col] = s;
}

// sum 4 split-K partials of gemm6 -> final out
__global__ __launch_bounds__(256) void out_reduce(
    const float* __restrict__ part, float* __restrict__ out)
{
    int i = blockIdx.x * 256 + threadIdx.x;    // 524288 float4 groups
    float4 p0 = ((const float4*)part)[i];
    float4 p1 = ((const float4*)(part + 2097152))[i];
    float4 p2 = ((const float4*)(part + 4194304))[i];
    float4 p3 = ((const float4*)(part + 6291456))[i];
    float4 o = {p0.x + p1.x + p2.x + p3.x, p0.y + p1.y + p2.y + p3.y,
                p0.z + p1.z + p2.z + p3.z, p0.w + p1.w + p2.w + p3.w};
    ((float4*)out)[i] = o;
}

// ---------------------------------------------------------------------------
// depthwise causal conv1d (K=4) + bias + SiLU; bf16 in/out, 8 d's per thread.
// R16 (verified): rolling window over 4 consecutive l per thread — reads 7
// rows per 4 outputs (was 4 reads per 1 output): traffic ~40 MB -> ~22 MB.
// Lane i owns d8 = i*8, so all loads stay 1 KB/wave coalesced.
__global__ __launch_bounds__(256) void conv_silu8(
    const unsigned short* __restrict__ aB,
    const float* __restrict__ cw, const float* __restrict__ cb,
    unsigned short* __restrict__ aConvB)
{
    int blk = blockIdx.x;                      // 512 = b*256 + lg
    int lg = blk & 255, b = blk >> 8;
    int l0 = lg << 2;
    int d8 = threadIdx.x << 3;
    const unsigned short* base = aB + (size_t)(b * LSEQ + l0) * 2048 + d8;
    unsigned short* obase = aConvB + (size_t)(b * LSEQ + l0) * 2048 + d8;
    const ushort8 z8 = {0, 0, 0, 0, 0, 0, 0, 0};
    ushort8 xm3, xm2, xm1;
    if (l0 > 0) {                              // l0 multiple of 4 -> l0>=3
        xm3 = *(const ushort8*)(base - 3 * 2048);
        xm2 = *(const ushort8*)(base - 2 * 2048);
        xm1 = *(const ushort8*)(base - 1 * 2048);
    } else { xm3 = z8; xm2 = z8; xm1 = z8; }
    float4 cb0 = *(const float4*)(cb + d8);
    float4 cb1 = *(const float4*)(cb + d8 + 4);
    float bv[8] = {cb0.x, cb0.y, cb0.z, cb0.w, cb1.x, cb1.y, cb1.z, cb1.w};
    float4 w0[8];
#pragma unroll
    for (int j = 0; j < 8; j++) w0[j] = *(const float4*)(cw + (size_t)(d8 + j) * 4);
#pragma unroll
    for (int t = 0; t < 4; t++) {
        ushort8 x0 = *(const ushort8*)(base + t * 2048);
        ushort8 o;
#pragma unroll
        for (int j = 0; j < 8; j++) {
            float acc = bv[j];
            acc = fmaf(b2f(x0[j]),  w0[j].w, acc);
            acc = fmaf(b2f(xm1[j]), w0[j].z, acc);
            acc = fmaf(b2f(xm2[j]), w0[j].y, acc);
            acc = fmaf(b2f(xm3[j]), w0[j].x, acc);
            o[j] = f2b(siluf(acc));
        }
        *(ushort8*)(obase + t * 2048) = o;
        xm3 = xm2; xm2 = xm1; xm1 = x0;
    }
}

// ---------------------------------------------------------------------------
// Chunk-parallel scan, 64 chunks x 16 steps, bf16 inputs (fp32 compute,
// fp32 hend — R15's bf16-hend was neutral-negative, reverted).
// prod factorization: chunk prod[s] = expA[s]^CH * prod(delta); phase A
// stores only P = prod(delta) (1 float), phase B rebuilds expA^16 by squaring.
// hend idx(b,c,s,d) = (((b*64+c)*16+s)<<11)+d ; P idx = (b*64+c)*2048+d.
__global__ __launch_bounds__(256) void scan_phaseA(
    const unsigned short* __restrict__ deltaB,
    const unsigned short* __restrict__ aConvB,
    const float* __restrict__ bc32, const float* __restrict__ A_param,
    float* __restrict__ hend, float* __restrict__ Pd)
{
    int blk = blockIdx.x;                      // 1024
    int d = ((blk & 7) << 8) + threadIdx.x;
    int c = (blk >> 3) & 63;
    int b = blk >> 9;
    float expA[16], h[16];
#pragma unroll
    for (int s = 0; s < 16; s++) {
        expA[s] = expf(-A_param[d * 16 + s]);
        h[s] = 0.f;
    }
    float P = 1.f;
    int r0 = b * LSEQ + c * CH;
    const unsigned short* dp = deltaB + (size_t)r0 * D_MODEL + d;
    const unsigned short* ap = aConvB + (size_t)r0 * D_MODEL + d;
    const float4* bp = (const float4*)(bc32 + (size_t)r0 * 32);
    float dlt = b2f(*dp), av = b2f(*ap);
    float4 B0 = bp[0], B1 = bp[1], B2 = bp[2], B3 = bp[3];
    for (int l = 0; l < CH; l++) {
        dp += 2048; ap += 2048; bp += 8;       // prefetch l+1 (lands in ws, safe)
        float nd = b2f(*dp), na = b2f(*ap);
        float4 nB0 = bp[0], nB1 = bp[1], nB2 = bp[2], nB3 = bp[3];
        float Bv[16] = {B0.x, B0.y, B0.z, B0.w, B1.x, B1.y, B1.z, B1.w,
                        B2.x, B2.y, B2.z, B2.w, B3.x, B3.y, B3.z, B3.w};
        float x = dlt * av;
        P *= dlt;
#pragma unroll
        for (int s = 0; s < 16; s++)
            h[s] = fmaf(expA[s] * dlt, h[s], Bv[s] * x);
        dlt = nd; av = na; B0 = nB0; B1 = nB1; B2 = nB2; B3 = nB3;
    }
    size_t base = (((size_t)(b * 64 + c) * 16) << 11) + d;
#pragma unroll
    for (int s = 0; s < 16; s++)
        hend[base + ((size_t)s << 11)] = h[s];
    Pd[(size_t)(b * 64 + c) * 2048 + d] = P;
}

// chunk prefix: overwrite hend[c] with state ENTERING chunk c.
// R16 (verified): depth-4 software prefetch (was depth-1). 65536 indep
// chains at only ~4 waves/CU -> per-iter exposed L2 latency dominated;
// 8 loads in flight per thread. All register names static (rule #20).
__global__ __launch_bounds__(256) void scan_phaseB2(
    float* __restrict__ hend, const float* __restrict__ Pd,
    const float* __restrict__ A_param)
{
    int t = blockIdx.x * 256 + threadIdx.x;    // 65536
    int d = t & 2047, s = (t >> 11) & 15, b = t >> 15;
    float e = expf(-A_param[d * 16 + s]);
    float e2 = e * e, e4 = e2 * e2, e8 = e4 * e4;
    float eCH = e8 * e8;                       // expA^16
    size_t idx = (((size_t)(b * 64) * 16 + s) << 11) + d;
    const size_t cs = (size_t)16 << 11;
    size_t pidx = (size_t)(b * 64) * 2048 + d;
    float h = 0.f;
    float he0 = hend[idx], he1 = hend[idx + cs];
    float he2 = hend[idx + 2 * cs], he3 = hend[idx + 3 * cs];
    float P0 = Pd[pidx], P1 = Pd[pidx + 2048];
    float P2 = Pd[pidx + 2 * 2048], P3 = Pd[pidx + 3 * 2048];
    for (int c = 0; c < NCH; c += 4) {
        size_t idx4 = idx + 4 * cs;
        size_t pidx4 = pidx + (size_t)4 * 2048;
        float nh0 = 0.f, nh1 = 0.f, nh2 = 0.f, nh3 = 0.f;
        float nP0 = 0.f, nP1 = 0.f, nP2 = 0.f, nP3 = 0.f;
        if (c + 4 < NCH) {
            nh0 = hend[idx4];          nh1 = hend[idx4 + cs];
            nh2 = hend[idx4 + 2 * cs]; nh3 = hend[idx4 + 3 * cs];
            nP0 = Pd[pidx4];           nP1 = Pd[pidx4 + 2048];
            nP2 = Pd[pidx4 + 2 * 2048]; nP3 = Pd[pidx4 + 3 * 2048];
        }
        hend[idx] = h;            h = fmaf(eCH * P0, h, he0);
        hend[idx + cs] = h;       h = fmaf(eCH * P1, h, he1);
        hend[idx + 2 * cs] = h;   h = fmaf(eCH * P2, h, he2);
        hend[idx + 3 * cs] = h;   h = fmaf(eCH * P3, h, he3);
        idx = idx4; pidx = pidx4;
        he0 = nh0; he1 = nh1; he2 = nh2; he3 = nh3;
        P0 = nP0; P1 = nP1; P2 = nP2; P3 = nP3;
    }
}

__global__ __launch_bounds__(256) void scan_phaseC(
    const unsigned short* __restrict__ deltaB,
    const unsigned short* __restrict__ aConvB,
    const unsigned short* __restrict__ gateB,
    const float* __restrict__ bc32,
    const float* __restrict__ A_param, const float* __restrict__ D_param,
    const float* __restrict__ hend, unsigned short* __restrict__ outB)
{
    int blk = blockIdx.x;                      // 1024
    int d = ((blk & 7) << 8) + threadIdx.x;
    int c = (blk >> 3) & 63;
    int b = blk >> 9;
    float expA[16], h[16];
    size_t base = (((size_t)(b * 64 + c) * 16) << 11) + d;
#pragma unroll
    for (int s = 0; s < 16; s++) {
        expA[s] = expf(-A_param[d * 16 + s]);
        h[s] = hend[base + ((size_t)s << 11)];
    }
    float Dp = D_param[d];
    int r0 = b * LSEQ + c * CH;
    const unsigned short* dp = deltaB + (size_t)r0 * D_MODEL + d;
    const unsigned short* ap = aConvB + (size_t)r0 * D_MODEL + d;
    const unsigned short* gp = gateB + (size_t)r0 * 2048 + d;
    const float4* bp = (const float4*)(bc32 + (size_t)r0 * 32);
    unsigned short* op = outB + (size_t)r0 * D_MODEL + d;
    float dlt = b2f(*dp), av = b2f(*ap), g = b2f(*gp);
    float4 B0 = bp[0], B1 = bp[1], B2 = bp[2], B3 = bp[3];
    float4 C0 = bp[4], C1 = bp[5], C2 = bp[6], C3 = bp[7];
    for (int l = 0; l < CH; l++) {
        dp += 2048; ap += 2048; gp += 2048; bp += 8;
        float nd = b2f(*dp), na = b2f(*ap), ng = b2f(*gp);
        float4 nB0 = bp[0], nB1 = bp[1], nB2 = bp[2], nB3 = bp[3];
        float4 nC0 = bp[4], nC1 = bp[5], nC2 = bp[6], nC3 = bp[7];
        float Bv[16] = {B0.x, B0.y, B0.z, B0.w, B1.x, B1.y, B1.z, B1.w,
                        B2.x, B2.y, B2.z, B2.w, B3.x, B3.y, B3.z, B3.w};
        float Cv[16] = {C0.x, C0.y, C0.z, C0.w, C1.x, C1.y, C1.z, C1.w,
                        C2.x, C2.y, C2.z, C2.w, C3.x, C3.y, C3.z, C3.w};
        float x = dlt * av;
        float acc = 0.f;
#pragma unroll
        for (int s = 0; s < 16; s++) {
            float Ab = expA[s] * dlt;
            h[s] = fmaf(Ab, h[s], Bv[s] * x);
            acc = fmaf(h[s], Cv[s], acc);
        }
        *op = f2b((acc + Dp * av) * siluf(g));
        op += D_MODEL;
        dlt = nd; av = na; g = ng;
        B0 = nB0; B1 = nB1; B2 = nB2; B3 = nB3;
        C0 = nC0; C1 = nC1; C2 = nC2; C3 = nC3;
    }
}

extern "C" void kernel_launch(void* const* d_in, const int* in_sizes, int n_in,
                              void* d_out, int out_size, void* d_ws, size_t ws_size,
                              hipStream_t stream) {
    const float* seq = (const float*)d_in[0];
    const float* w_in = (const float*)d_in[1];
    const float* w_out = (const float*)d_in[2];
    const float* w_B = (const float*)d_in[3];
    const float* w_C = (const float*)d_in[4];
    const float* w_D1 = (const float*)d_in[5];
    const float* w_D2 = (const float*)d_in[6];
    const float* conv_w = (const float*)d_in[7];
    const float* conv_b = (const float*)d_in[8];
    const float* A_param = (const float*)d_in[9];
    const float* D_param = (const float*)d_in[10];
    float* out = (float*)d_out;

    // fp32 region (floats)
    float* bc32  = (float*)d_ws;                   // 65,536
    float* part  = bc32 + (size_t)65536;           // 2,621,440 (dead after reduce)
    float* part6 = part + (size_t)2621440;         // 8,388,608 (gemm6 partials)
    float* Pd    = part;                           // overlay: 262,144 ✓ (part dead)
    float* hend  = part6;                          // overlay: 4,194,304 ✓ (hend dead
                                                   //  before gemm6 writes part6)
    // bf16 region
    unsigned short* seq_b  = (unsigned short*)(part6 + 8388608);
    unsigned short* win_b  = seq_b + (size_t)2097152;
    unsigned short* wout_b = win_b + (size_t)4194304;
    unsigned short* wbcd_b = wout_b + (size_t)2097152;  // [160,2048]
    unsigned short* wd2_b  = wbcd_b + (size_t)327680;   // [2048,128]
    unsigned short* aB     = wd2_b + (size_t)262144;    // [2048,2048]
    unsigned short* aConvB = aB + (size_t)4194304;      // [2048,2048]
    unsigned short* deltaB = aConvB + (size_t)4194304;  // [2048,2048]
    unsigned short* gateB  = deltaB + (size_t)4194304;  // [2048,2048]
    unsigned short* outB   = gateB + (size_t)4194304;   // [2048,2048]
    unsigned short* bcdB   = outB + (size_t)4194304;    // [2048,160]

    // 0) casts
    cast_all<<<dim3(4384), 256, 0, stream>>>(seq, w_in, w_out, w_B, w_C, w_D1, w_D2,
                                             seq_b, win_b, wout_b, wbcd_b, wd2_b);
    // 1) [a|gate] = seq @ w_in^T  [2048 x 4096] K=1024; long-K -> UNR
    gemm_db<64, true><<<dim3(64, 16), 256, 0, stream>>>(seq_b, 1024, win_b, 1024,
                                                  (float*)aB, 2048, 0, 4096, 1024,
                                                  nullptr, gateB, 5);
    // 2) conv + SiLU (bf16 in/out, 8-wide, 4-l rolling window)
    conv_silu8<<<dim3(512), 256, 0, stream>>>(aB, conv_w, conv_b, aConvB);
    // 3) bcd split-K x8, TN=64, K=256/block -> short-K, runtime-buf loop
    gemm_db<64, false><<<dim3(3, 16, 8), 256, 0, stream>>>(aConvB, 2048, wbcd_b, 2048,
                                                    part, 160, 327680, 160, 256,
                                                    nullptr, nullptr, 0);
    bcd_reduce<<<dim3(1280), 256, 0, stream>>>(part, bcdB, bc32);
    // 4) deltaB = bf16(softplus(D + d1 @ wD2^T))  K=128 -> short-K, runtime-buf
    gemm_db<64, false><<<dim3(32, 16), 256, 0, stream>>>(bcdB + 32, 160, wd2_b, 128,
                                                  (float*)deltaB, 2048, 0, 2048, 128,
                                                  D_param, nullptr, 2);
    // 5) chunk-parallel scan (64 chunks x 16 steps; bf16 datapath, fp32 hend)
    scan_phaseA<<<dim3(1024), 256, 0, stream>>>(deltaB, aConvB, bc32, A_param,
                                                hend, Pd);
    scan_phaseB2<<<dim3(256), 256, 0, stream>>>(hend, Pd, A_param);
    scan_phaseC<<<dim3(1024), 256, 0, stream>>>(deltaB, aConvB, gateB, bc32,
                                                A_param, D_param, hend, outB);
    // 6) out = ssm_out @ w_out^T  K=512/block -> long-K -> UNR; split-K x4
    gemm_db<64, true><<<dim3(16, 16, 4), 256, 0, stream>>>(outB, 2048, wout_b, 2048,
                                                     part6, 1024, 2097152, 1024, 512,
                                                     nullptr, nullptr, 0);
    out_reduce<<<dim3(2048), 256, 0, stream>>>(part6, out);
}

// Round 6
// 235.615 us; speedup vs baseline: 1.0386x; 1.0386x over previous
//
#include <hip/hip_runtime.h>
#include <math.h>

#define B_SZ 2
#define LSEQ 1024
#define D_INP 1024
#define D_MODEL 2048
#define D_STATE 16
#define D_DISCR 128
#define MROWS (B_SZ * LSEQ)
#define NCH 64
#define CH 16

typedef __bf16 bf16x8 __attribute__((ext_vector_type(8)));
typedef float f32x4 __attribute__((ext_vector_type(4)));
typedef unsigned short ushort8 __attribute__((ext_vector_type(8)));

__device__ __forceinline__ float siluf(float x) { return x / (1.f + expf(-x)); }
__device__ __forceinline__ float softplusf(float x) {
    return fmaxf(x, 0.f) + log1pf(expf(-fabsf(x)));
}
__device__ __forceinline__ unsigned short f2b(float f) {
    unsigned u = __builtin_bit_cast(unsigned, f);
    u = u + 0x7fffu + ((u >> 16) & 1u);
    return (unsigned short)(u >> 16);
}
__device__ __forceinline__ float b2f(unsigned short u) {
    return __builtin_bit_cast(float, ((unsigned)u) << 16);
}

// ---------------------------------------------------------------------------
__global__ __launch_bounds__(256) void cast_all(
    const float* __restrict__ seq, const float* __restrict__ w_in,
    const float* __restrict__ w_out, const float* __restrict__ w_B,
    const float* __restrict__ w_C, const float* __restrict__ w_D1,
    const float* __restrict__ w_D2,
    unsigned short* __restrict__ seq_b, unsigned short* __restrict__ win_b,
    unsigned short* __restrict__ wout_b, unsigned short* __restrict__ wbcd_b,
    unsigned short* __restrict__ wd2_b)
{
    int i = blockIdx.x * 256 + threadIdx.x;
    const float* src; unsigned short* dst; int off;
    if      (i < 262144)  { src = seq;  dst = seq_b;          off = i; }
    else if (i < 786432)  { src = w_in; dst = win_b;          off = i - 262144; }
    else if (i < 1048576) { src = w_out; dst = wout_b;        off = i - 786432; }
    else if (i < 1052672) { src = w_B;  dst = wbcd_b;         off = i - 1048576; }
    else if (i < 1056768) { src = w_C;  dst = wbcd_b + 32768; off = i - 1052672; }
    else if (i < 1089536) { src = w_D1; dst = wbcd_b + 65536; off = i - 1056768; }
    else if (i < 1122304) { src = w_D2; dst = wd2_b;          off = i - 1089536; }
    else return;
    const float4* p = (const float4*)(src + (size_t)off * 8);
    float4 a = p[0], b = p[1];
    ushort8 o = {f2b(a.x), f2b(a.y), f2b(a.z), f2b(a.w),
                 f2b(b.x), f2b(b.y), f2b(b.z), f2b(b.w)};
    *(ushort8*)(dst + (size_t)off * 8) = o;
}

// ---------------------------------------------------------------------------
// bf16 MFMA GEMM-NT — R12/R17 structure: 128xTN tile, BK=32, VGPR-staged
// single-slab prefetch double buffer, 1 barrier/K-iter, XOR-swizzled
// unpadded LDS (0 conflicts). R20: loop flavor per call site (UNR=true:
// compile-time buffer index, long-K; UNR=false: runtime buf, short-K).
// R20 post-mortem: UNR drops VALUBusy 46->19 but time unchanged — kernel
// is latency/barrier-bound, not VALU-bound. 41 µs is this structure's
// floor at 4 blocks/CU. Sweep: 128x64 @4/CU = 41 (R12); 64x64 = 51 (R14);
// depth-2 = 54 (R11); gll = neutral (R13); padded = 71 (R6); 128x128
// @2/CU = 85 (R16); A-via-registers = 51.5 (R18); short-K pinned unroll
// = 75.6 on gemm4 (R19 — destroyed compiler's short-pipeline schedule).
// Block does K-chunk [z*K, z*K+K) -> Cbase + z*partStride.
// B rows past N read unguarded (must be allocated); masked at store.
// epi: 0 fp32 store; 2 softplus(bias[col]+acc) -> bf16 (Cbase as u16);
//      5 split both-bf16: col<2048 -> (u16*)Cbase, col>=2048 -> C2.
template <int TN, bool UNR>
__global__ __launch_bounds__(256) void gemm_db(
    const unsigned short* __restrict__ A, int lda,
    const unsigned short* __restrict__ B, int ldb,
    float* __restrict__ Cbase, int ldc, size_t partStride,
    int N, int K, const float* __restrict__ bias,
    unsigned short* __restrict__ C2, int epi)
{
    __shared__ unsigned short As[2][128 * 32];
    __shared__ unsigned short Bs[2][TN * 32];
    const int t = threadIdx.x;
    const int w = t >> 6, lane = t & 63;
    const int fr = lane & 15, fq = lane >> 4;
    const int row0 = blockIdx.y * 128, col0 = blockIdx.x * TN;
    const int kz = blockIdx.z * K;
    const int sr = t >> 2, sq = t & 3;
    const int sqz = sq ^ ((sr >> 1) & 3);      // swizzled store chunk
    const int qa = fq ^ ((fr >> 1) & 3);       // swizzled read chunk

    constexpr int NI = (TN == 128) ? 4 : 2;
    const int rbase = (TN == 128) ? (w >> 1) * 64 : w * 32;
    const int cbase = (TN == 128) ? (w & 1) * 64 : 0;

    const unsigned short* gA0 = A + (size_t)(row0 + sr) * lda + kz + sq * 8;
    const unsigned short* gA1 = gA0 + (size_t)64 * lda;
    const unsigned short* gB0 = B + (size_t)(col0 + sr) * ldb + kz + sq * 8;
    const unsigned short* gB1 = gB0 + (size_t)64 * ldb;

    f32x4 acc[NI][4];
#pragma unroll
    for (int i = 0; i < NI; i++)
#pragma unroll
        for (int j = 0; j < 4; j++) acc[i][j] = (f32x4){0.f, 0.f, 0.f, 0.f};

    // prologue: stage slab 0 into buffer 0
    ushort8 a0 = *(const ushort8*)gA0;
    ushort8 a1 = *(const ushort8*)gA1;
    ushort8 b0 = *(const ushort8*)gB0;
    ushort8 b1;
    if (TN == 128) b1 = *(const ushort8*)gB1;
    *(ushort8*)&As[0][sr * 32 + sqz * 8] = a0;
    *(ushort8*)&As[0][(64 + sr) * 32 + sqz * 8] = a1;
    *(ushort8*)&Bs[0][sr * 32 + sqz * 8] = b0;
    if (TN == 128) *(ushort8*)&Bs[0][(64 + sr) * 32 + sqz * 8] = b1;
    __syncthreads();

    if constexpr (UNR) {
        const int nhalf = K / 32;              // even at all UNR call sites
#pragma unroll 1
        for (int p = 0; p < nhalf; p += 2) {
#pragma unroll
            for (int h = 0; h < 2; ++h) {      // h = compile-time buffer idx
                const int k0 = (p + h) * 32;
                const bool more = (k0 + 32 < K);
                if (more) {                    // next-slab loads in flight
                    gA0 += 32; gA1 += 32; gB0 += 32; gB1 += 32;
                    a0 = *(const ushort8*)gA0;
                    a1 = *(const ushort8*)gA1;
                    b0 = *(const ushort8*)gB0;
                    if (TN == 128) b1 = *(const ushort8*)gB1;
                }
                bf16x8 af[NI], bfr[4];
#pragma unroll
                for (int i = 0; i < NI; i++) {
                    ushort8 u = *(const ushort8*)&As[h][(rbase + i * 16 + fr) * 32 + qa * 8];
                    af[i] = __builtin_bit_cast(bf16x8, u);
                }
#pragma unroll
                for (int j = 0; j < 4; j++) {
                    ushort8 u = *(const ushort8*)&Bs[h][(cbase + j * 16 + fr) * 32 + qa * 8];
                    bfr[j] = __builtin_bit_cast(bf16x8, u);
                }
#pragma unroll
                for (int i = 0; i < NI; i++)
#pragma unroll
                    for (int j = 0; j < 4; j++)
                        acc[i][j] = __builtin_amdgcn_mfma_f32_16x16x32_bf16(
                            af[i], bfr[j], acc[i][j], 0, 0, 0);
                if (more) {                    // vmcnt wait lands here, post-MFMA
                    *(ushort8*)&As[h ^ 1][sr * 32 + sqz * 8] = a0;
                    *(ushort8*)&As[h ^ 1][(64 + sr) * 32 + sqz * 8] = a1;
                    *(ushort8*)&Bs[h ^ 1][sr * 32 + sqz * 8] = b0;
                    if (TN == 128) *(ushort8*)&Bs[h ^ 1][(64 + sr) * 32 + sqz * 8] = b1;
                    __syncthreads();
                }
            }
        }
    } else {
        int buf = 0;
        for (int k0 = 0; k0 < K; k0 += 32) {
            const bool more = (k0 + 32 < K);
            if (more) {                        // next-slab loads in flight
                gA0 += 32; gA1 += 32; gB0 += 32; gB1 += 32;
                a0 = *(const ushort8*)gA0;
                a1 = *(const ushort8*)gA1;
                b0 = *(const ushort8*)gB0;
                if (TN == 128) b1 = *(const ushort8*)gB1;
            }
            bf16x8 af[NI], bfr[4];
#pragma unroll
            for (int i = 0; i < NI; i++) {
                ushort8 u = *(const ushort8*)&As[buf][(rbase + i * 16 + fr) * 32 + qa * 8];
                af[i] = __builtin_bit_cast(bf16x8, u);
            }
#pragma unroll
            for (int j = 0; j < 4; j++) {
                ushort8 u = *(const ushort8*)&Bs[buf][(cbase + j * 16 + fr) * 32 + qa * 8];
                bfr[j] = __builtin_bit_cast(bf16x8, u);
            }
#pragma unroll
            for (int i = 0; i < NI; i++)
#pragma unroll
                for (int j = 0; j < 4; j++)
                    acc[i][j] = __builtin_amdgcn_mfma_f32_16x16x32_bf16(
                        af[i], bfr[j], acc[i][j], 0, 0, 0);
            if (more) {
                int nb = buf ^ 1;              // vmcnt wait lands here, post-MFMA
                *(ushort8*)&As[nb][sr * 32 + sqz * 8] = a0;
                *(ushort8*)&As[nb][(64 + sr) * 32 + sqz * 8] = a1;
                *(ushort8*)&Bs[nb][sr * 32 + sqz * 8] = b0;
                if (TN == 128) *(ushort8*)&Bs[nb][(64 + sr) * 32 + sqz * 8] = b1;
                __syncthreads();
                buf = nb;
            }
        }
    }

    float* C = Cbase + (size_t)blockIdx.z * partStride;
#pragma unroll
    for (int i = 0; i < NI; i++) {
#pragma unroll
        for (int r = 0; r < 4; r++) {
            int row = row0 + rbase + i * 16 + fq * 4 + r;
#pragma unroll
            for (int j = 0; j < 4; j++) {   // j-inner: contiguous write runs
                int col = col0 + cbase + j * 16 + fr;
                if (col >= N) continue;
                float v = acc[i][j][r];
                if (epi == 0) C[(size_t)row * ldc + col] = v;
                else if (epi == 2)
                    ((unsigned short*)Cbase)[(size_t)row * ldc + col] =
                        f2b(softplusf(bias[col] + v));
                else {
                    unsigned short v16 = f2b(v);
                    if (col < 2048) ((unsigned short*)Cbase)[(size_t)row * 2048 + col] = v16;
                    else C2[(size_t)row * 2048 + col - 2048] = v16;
                }
            }
        }
    }
}

// ---------------------------------------------------------------------------
// R21: dedicated delta GEMM (gemm4): [2048x2048] = bcdB_d1[2048x128] @
// wD2[2048x128]^T, K=128, epi = softplus(bias+acc) -> bf16.
// K=128 fits LDS whole: As 128x128 (32KB) + Bs 64x128 (16KB) = 48KB.
// Evidence (R19): the looped form at 2 blocks/CU, 4 K-iters, is pure
// latency (MfmaUtil 0.5%) — no steady state exists at 4 iters. So: issue
// all 12 global loads back-to-back (max MLP), ONE vmcnt drain + ONE
// barrier, then 4x8 MFMAs from LDS with no further sync. Same XOR-swizzle
// per 32-col slab as gemm_db (slab s at offset s*TILE*32).
__global__ __launch_bounds__(256) void gemm_d4(
    const unsigned short* __restrict__ A,   // bcdB+32, lda=160
    const unsigned short* __restrict__ B,   // wd2_b,  ldb=128
    unsigned short* __restrict__ Cb,        // deltaB (u16), ldc=2048
    const float* __restrict__ bias)
{
    __shared__ unsigned short As[4][128 * 32];
    __shared__ unsigned short Bs[4][64 * 32];
    const int t = threadIdx.x;
    const int w = t >> 6, lane = t & 63;
    const int fr = lane & 15, fq = lane >> 4;
    const int row0 = blockIdx.y * 128, col0 = blockIdx.x * 64;
    const int sr = t >> 2, sq = t & 3;
    const int sqz = sq ^ ((sr >> 1) & 3);
    const int qa = fq ^ ((fr >> 1) & 3);
    const int rbase = w * 32;

    ushort8 a0[4], a1[4], b0[4];
#pragma unroll
    for (int s = 0; s < 4; s++) {
        a0[s] = *(const ushort8*)(A + (size_t)(row0 + sr) * 160 + s * 32 + sq * 8);
        a1[s] = *(const ushort8*)(A + (size_t)(row0 + 64 + sr) * 160 + s * 32 + sq * 8);
        b0[s] = *(const ushort8*)(B + (size_t)(col0 + sr) * 128 + s * 32 + sq * 8);
    }
#pragma unroll
    for (int s = 0; s < 4; s++) {
        *(ushort8*)&As[s][sr * 32 + sqz * 8] = a0[s];
        *(ushort8*)&As[s][(64 + sr) * 32 + sqz * 8] = a1[s];
        *(ushort8*)&Bs[s][sr * 32 + sqz * 8] = b0[s];
    }
    __syncthreads();

    f32x4 acc[2][4];
#pragma unroll
    for (int i = 0; i < 2; i++)
#pragma unroll
        for (int j = 0; j < 4; j++) acc[i][j] = (f32x4){0.f, 0.f, 0.f, 0.f};

#pragma unroll
    for (int s = 0; s < 4; s++) {
        bf16x8 af[2], bfr[4];
#pragma unroll
        for (int i = 0; i < 2; i++) {
            ushort8 u = *(const ushort8*)&As[s][(rbase + i * 16 + fr) * 32 + qa * 8];
            af[i] = __builtin_bit_cast(bf16x8, u);
        }
#pragma unroll
        for (int j = 0; j < 4; j++) {
            ushort8 u = *(const ushort8*)&Bs[s][(j * 16 + fr) * 32 + qa * 8];
            bfr[j] = __builtin_bit_cast(bf16x8, u);
        }
#pragma unroll
        for (int i = 0; i < 2; i++)
#pragma unroll
            for (int j = 0; j < 4; j++)
                acc[i][j] = __builtin_amdgcn_mfma_f32_16x16x32_bf16(
                    af[i], bfr[j], acc[i][j], 0, 0, 0);
    }

#pragma unroll
    for (int i = 0; i < 2; i++) {
#pragma unroll
        for (int r = 0; r < 4; r++) {
            int row = row0 + rbase + i * 16 + fq * 4 + r;
#pragma unroll
            for (int j = 0; j < 4; j++) {
                int col = col0 + j * 16 + fr;
                Cb[(size_t)row * 2048 + col] =
                    f2b(softplusf(bias[col] + acc[i][j][r]));
            }
        }
    }
}

// ---------------------------------------------------------------------------
__global__ __launch_bounds__(256) void bcd_reduce(
    const float* __restrict__ part, unsigned short* __restrict__ bcdB,
    float* __restrict__ bc32)
{
    int t = blockIdx.x * 256 + threadIdx.x;
    if (t >= 327680) return;
    float s = 0.f;
#pragma unroll
    for (int z = 0; z < 8; z++) s += part[(size_t)z * 327680 + t];
    bcdB[t] = f2b(s);
    int col = t % 160;
    if (col < 32) bc32[(size_t)(t / 160) * 32 + col] = s;
}

// sum 4 split-K partials of gemm6 -> final out
__global__ __launch_bounds__(256) void out_reduce(
    const float* __restrict__ part, float* __restrict__ out)
{
    int i = blockIdx.x * 256 + threadIdx.x;    // 524288 float4 groups
    float4 p0 = ((const float4*)part)[i];
    float4 p1 = ((const float4*)(part + 2097152))[i];
    float4 p2 = ((const float4*)(part + 4194304))[i];
    float4 p3 = ((const float4*)(part + 6291456))[i];
    float4 o = {p0.x + p1.x + p2.x + p3.x, p0.y + p1.y + p2.y + p3.y,
                p0.z + p1.z + p2.z + p3.z, p0.w + p1.w + p2.w + p3.w};
    ((float4*)out)[i] = o;
}

// ---------------------------------------------------------------------------
// depthwise causal conv1d (K=4) + bias + SiLU; bf16 in/out, 8 d's per thread.
// R16 (verified): rolling window over 4 consecutive l per thread — reads 7
// rows per 4 outputs (was 4 reads per 1 output): traffic ~40 MB -> ~22 MB.
// Lane i owns d8 = i*8, so all loads stay 1 KB/wave coalesced.
__global__ __launch_bounds__(256) void conv_silu8(
    const unsigned short* __restrict__ aB,
    const float* __restrict__ cw, const float* __restrict__ cb,
    unsigned short* __restrict__ aConvB)
{
    int blk = blockIdx.x;                      // 512 = b*256 + lg
    int lg = blk & 255, b = blk >> 8;
    int l0 = lg << 2;
    int d8 = threadIdx.x << 3;
    const unsigned short* base = aB + (size_t)(b * LSEQ + l0) * 2048 + d8;
    unsigned short* obase = aConvB + (size_t)(b * LSEQ + l0) * 2048 + d8;
    const ushort8 z8 = {0, 0, 0, 0, 0, 0, 0, 0};
    ushort8 xm3, xm2, xm1;
    if (l0 > 0) {                              // l0 multiple of 4 -> l0>=3
        xm3 = *(const ushort8*)(base - 3 * 2048);
        xm2 = *(const ushort8*)(base - 2 * 2048);
        xm1 = *(const ushort8*)(base - 1 * 2048);
    } else { xm3 = z8; xm2 = z8; xm1 = z8; }
    float4 cb0 = *(const float4*)(cb + d8);
    float4 cb1 = *(const float4*)(cb + d8 + 4);
    float bv[8] = {cb0.x, cb0.y, cb0.z, cb0.w, cb1.x, cb1.y, cb1.z, cb1.w};
    float4 w0[8];
#pragma unroll
    for (int j = 0; j < 8; j++) w0[j] = *(const float4*)(cw + (size_t)(d8 + j) * 4);
#pragma unroll
    for (int t = 0; t < 4; t++) {
        ushort8 x0 = *(const ushort8*)(base + t * 2048);
        ushort8 o;
#pragma unroll
        for (int j = 0; j < 8; j++) {
            float acc = bv[j];
            acc = fmaf(b2f(x0[j]),  w0[j].w, acc);
            acc = fmaf(b2f(xm1[j]), w0[j].z, acc);
            acc = fmaf(b2f(xm2[j]), w0[j].y, acc);
            acc = fmaf(b2f(xm3[j]), w0[j].x, acc);
            o[j] = f2b(siluf(acc));
        }
        *(ushort8*)(obase + t * 2048) = o;
        xm3 = xm2; xm2 = xm1; xm1 = x0;
    }
}

// ---------------------------------------------------------------------------
// Chunk-parallel scan, 64 chunks x 16 steps, bf16 inputs (fp32 compute,
// fp32 hend — R15's bf16-hend was neutral-negative, reverted).
// prod factorization: chunk prod[s] = expA[s]^CH * prod(delta); phase A
// stores only P = prod(delta) (1 float), phase B rebuilds expA^16 by squaring.
// hend idx(b,c,s,d) = (((b*64+c)*16+s)<<11)+d ; P idx = (b*64+c)*2048+d.
__global__ __launch_bounds__(256) void scan_phaseA(
    const unsigned short* __restrict__ deltaB,
    const unsigned short* __restrict__ aConvB,
    const float* __restrict__ bc32, const float* __restrict__ A_param,
    float* __restrict__ hend, float* __restrict__ Pd)
{
    int blk = blockIdx.x;                      // 1024
    int d = ((blk & 7) << 8) + threadIdx.x;
    int c = (blk >> 3) & 63;
    int b = blk >> 9;
    float expA[16], h[16];
#pragma unroll
    for (int s = 0; s < 16; s++) {
        expA[s] = expf(-A_param[d * 16 + s]);
        h[s] = 0.f;
    }
    float P = 1.f;
    int r0 = b * LSEQ + c * CH;
    const unsigned short* dp = deltaB + (size_t)r0 * D_MODEL + d;
    const unsigned short* ap = aConvB + (size_t)r0 * D_MODEL + d;
    const float4* bp = (const float4*)(bc32 + (size_t)r0 * 32);
    float dlt = b2f(*dp), av = b2f(*ap);
    float4 B0 = bp[0], B1 = bp[1], B2 = bp[2], B3 = bp[3];
    for (int l = 0; l < CH; l++) {
        dp += 2048; ap += 2048; bp += 8;       // prefetch l+1 (lands in ws, safe)
        float nd = b2f(*dp), na = b2f(*ap);
        float4 nB0 = bp[0], nB1 = bp[1], nB2 = bp[2], nB3 = bp[3];
        float Bv[16] = {B0.x, B0.y, B0.z, B0.w, B1.x, B1.y, B1.z, B1.w,
                        B2.x, B2.y, B2.z, B2.w, B3.x, B3.y, B3.z, B3.w};
        float x = dlt * av;
        P *= dlt;
#pragma unroll
        for (int s = 0; s < 16; s++)
            h[s] = fmaf(expA[s] * dlt, h[s], Bv[s] * x);
        dlt = nd; av = na; B0 = nB0; B1 = nB1; B2 = nB2; B3 = nB3;
    }
    size_t base = (((size_t)(b * 64 + c) * 16) << 11) + d;
#pragma unroll
    for (int s = 0; s < 16; s++)
        hend[base + ((size_t)s << 11)] = h[s];
    Pd[(size_t)(b * 64 + c) * 2048 + d] = P;
}

// chunk prefix: overwrite hend[c] with state ENTERING chunk c.
// R16 (verified): depth-4 software prefetch (was depth-1). 65536 indep
// chains at only ~4 waves/CU -> per-iter exposed L2 latency dominated;
// 8 loads in flight per thread. All register names static (rule #20).
__global__ __launch_bounds__(256) void scan_phaseB2(
    float* __restrict__ hend, const float* __restrict__ Pd,
    const float* __restrict__ A_param)
{
    int t = blockIdx.x * 256 + threadIdx.x;    // 65536
    int d = t & 2047, s = (t >> 11) & 15, b = t >> 15;
    float e = expf(-A_param[d * 16 + s]);
    float e2 = e * e, e4 = e2 * e2, e8 = e4 * e4;
    float eCH = e8 * e8;                       // expA^16
    size_t idx = (((size_t)(b * 64) * 16 + s) << 11) + d;
    const size_t cs = (size_t)16 << 11;
    size_t pidx = (size_t)(b * 64) * 2048 + d;
    float h = 0.f;
    float he0 = hend[idx], he1 = hend[idx + cs];
    float he2 = hend[idx + 2 * cs], he3 = hend[idx + 3 * cs];
    float P0 = Pd[pidx], P1 = Pd[pidx + 2048];
    float P2 = Pd[pidx + 2 * 2048], P3 = Pd[pidx + 3 * 2048];
    for (int c = 0; c < NCH; c += 4) {
        size_t idx4 = idx + 4 * cs;
        size_t pidx4 = pidx + (size_t)4 * 2048;
        float nh0 = 0.f, nh1 = 0.f, nh2 = 0.f, nh3 = 0.f;
        float nP0 = 0.f, nP1 = 0.f, nP2 = 0.f, nP3 = 0.f;
        if (c + 4 < NCH) {
            nh0 = hend[idx4];          nh1 = hend[idx4 + cs];
            nh2 = hend[idx4 + 2 * cs]; nh3 = hend[idx4 + 3 * cs];
            nP0 = Pd[pidx4];           nP1 = Pd[pidx4 + 2048];
            nP2 = Pd[pidx4 + 2 * 2048]; nP3 = Pd[pidx4 + 3 * 2048];
        }
        hend[idx] = h;            h = fmaf(eCH * P0, h, he0);
        hend[idx + cs] = h;       h = fmaf(eCH * P1, h, he1);
        hend[idx + 2 * cs] = h;   h = fmaf(eCH * P2, h, he2);
        hend[idx + 3 * cs] = h;   h = fmaf(eCH * P3, h, he3);
        idx = idx4; pidx = pidx4;
        he0 = nh0; he1 = nh1; he2 = nh2; he3 = nh3;
        P0 = nP0; P1 = nP1; P2 = nP2; P3 = nP3;
    }
}

__global__ __launch_bounds__(256) void scan_phaseC(
    const unsigned short* __restrict__ deltaB,
    const unsigned short* __restrict__ aConvB,
    const unsigned short* __restrict__ gateB,
    const float* __restrict__ bc32,
    const float* __restrict__ A_param, const float* __restrict__ D_param,
    const float* __restrict__ hend, unsigned short* __restrict__ outB)
{
    int blk = blockIdx.x;                      // 1024
    int d = ((blk & 7) << 8) + threadIdx.x;
    int c = (blk >> 3) & 63;
    int b = blk >> 9;
    float expA[16], h[16];
    size_t base = (((size_t)(b * 64 + c) * 16) << 11) + d;
#pragma unroll
    for (int s = 0; s < 16; s++) {
        expA[s] = expf(-A_param[d * 16 + s]);
        h[s] = hend[base + ((size_t)s << 11)];
    }
    float Dp = D_param[d];
    int r0 = b * LSEQ + c * CH;
    const unsigned short* dp = deltaB + (size_t)r0 * D_MODEL + d;
    const unsigned short* ap = aConvB + (size_t)r0 * D_MODEL + d;
    const unsigned short* gp = gateB + (size_t)r0 * 2048 + d;
    const float4* bp = (const float4*)(bc32 + (size_t)r0 * 32);
    unsigned short* op = outB + (size_t)r0 * D_MODEL + d;
    float dlt = b2f(*dp), av = b2f(*ap), g = b2f(*gp);
    float4 B0 = bp[0], B1 = bp[1], B2 = bp[2], B3 = bp[3];
    float4 C0 = bp[4], C1 = bp[5], C2 = bp[6], C3 = bp[7];
    for (int l = 0; l < CH; l++) {
        dp += 2048; ap += 2048; gp += 2048; bp += 8;
        float nd = b2f(*dp), na = b2f(*ap), ng = b2f(*gp);
        float4 nB0 = bp[0], nB1 = bp[1], nB2 = bp[2], nB3 = bp[3];
        float4 nC0 = bp[4], nC1 = bp[5], nC2 = bp[6], nC3 = bp[7];
        float Bv[16] = {B0.x, B0.y, B0.z, B0.w, B1.x, B1.y, B1.z, B1.w,
                        B2.x, B2.y, B2.z, B2.w, B3.x, B3.y, B3.z, B3.w};
        float Cv[16] = {C0.x, C0.y, C0.z, C0.w, C1.x, C1.y, C1.z, C1.w,
                        C2.x, C2.y, C2.z, C2.w, C3.x, C3.y, C3.z, C3.w};
        float x = dlt * av;
        float acc = 0.f;
#pragma unroll
        for (int s = 0; s < 16; s++) {
            float Ab = expA[s] * dlt;
            h[s] = fmaf(Ab, h[s], Bv[s] * x);
            acc = fmaf(h[s], Cv[s], acc);
        }
        *op = f2b((acc + Dp * av) * siluf(g));
        op += D_MODEL;
        dlt = nd; av = na; g = ng;
        B0 = nB0; B1 = nB1; B2 = nB2; B3 = nB3;
        C0 = nC0; C1 = nC1; C2 = nC2; C3 = nC3;
    }
}

extern "C" void kernel_launch(void* const* d_in, const int* in_sizes, int n_in,
                              void* d_out, int out_size, void* d_ws, size_t ws_size,
                              hipStream_t stream) {
    const float* seq = (const float*)d_in[0];
    const float* w_in = (const float*)d_in[1];
    const float* w_out = (const float*)d_in[2];
    const float* w_B = (const float*)d_in[3];
    const float* w_C = (const float*)d_in[4];
    const float* w_D1 = (const float*)d_in[5];
    const float* w_D2 = (const float*)d_in[6];
    const float* conv_w = (const float*)d_in[7];
    const float* conv_b = (const float*)d_in[8];
    const float* A_param = (const float*)d_in[9];
    const float* D_param = (const float*)d_in[10];
    float* out = (float*)d_out;

    // fp32 region (floats)
    float* bc32  = (float*)d_ws;                   // 65,536
    float* part  = bc32 + (size_t)65536;           // 2,621,440 (dead after reduce)
    float* part6 = part + (size_t)2621440;         // 8,388,608 (gemm6 partials)
    float* Pd    = part;                           // overlay: 262,144 ✓ (part dead)
    float* hend  = part6;                          // overlay: 4,194,304 ✓ (hend dead
                                                   //  before gemm6 writes part6)
    // bf16 region
    unsigned short* seq_b  = (unsigned short*)(part6 + 8388608);
    unsigned short* win_b  = seq_b + (size_t)2097152;
    unsigned short* wout_b = win_b + (size_t)4194304;
    unsigned short* wbcd_b = wout_b + (size_t)2097152;  // [160,2048]
    unsigned short* wd2_b  = wbcd_b + (size_t)327680;   // [2048,128]
    unsigned short* aB     = wd2_b + (size_t)262144;    // [2048,2048]
    unsigned short* aConvB = aB + (size_t)4194304;      // [2048,2048]
    unsigned short* deltaB = aConvB + (size_t)4194304;  // [2048,2048]
    unsigned short* gateB  = deltaB + (size_t)4194304;  // [2048,2048]
    unsigned short* outB   = gateB + (size_t)4194304;   // [2048,2048]
    unsigned short* bcdB   = outB + (size_t)4194304;    // [2048,160]

    // 0) casts
    cast_all<<<dim3(4384), 256, 0, stream>>>(seq, w_in, w_out, w_B, w_C, w_D1, w_D2,
                                             seq_b, win_b, wout_b, wbcd_b, wd2_b);
    // 1) [a|gate] = seq @ w_in^T  [2048 x 4096] K=1024; long-K -> UNR
    gemm_db<64, true><<<dim3(64, 16), 256, 0, stream>>>(seq_b, 1024, win_b, 1024,
                                                  (float*)aB, 2048, 0, 4096, 1024,
                                                  nullptr, gateB, 5);
    // 2) conv + SiLU (bf16 in/out, 8-wide, 4-l rolling window)
    conv_silu8<<<dim3(512), 256, 0, stream>>>(aB, conv_w, conv_b, aConvB);
    // 3) bcd split-K x8, TN=64, K=256/block -> short-K, runtime-buf loop
    gemm_db<64, false><<<dim3(3, 16, 8), 256, 0, stream>>>(aConvB, 2048, wbcd_b, 2048,
                                                    part, 160, 327680, 160, 256,
                                                    nullptr, nullptr, 0);
    bcd_reduce<<<dim3(1280), 256, 0, stream>>>(part, bcdB, bc32);
    // 4) deltaB = bf16(softplus(D + d1 @ wD2^T))  K=128 -> R21 whole-K
    //    single-stage kernel (1 barrier total)
    gemm_d4<<<dim3(32, 16), 256, 0, stream>>>(bcdB + 32, wd2_b,
                                              deltaB, D_param);
    // 5) chunk-parallel scan (64 chunks x 16 steps; bf16 datapath, fp32 hend)
    scan_phaseA<<<dim3(1024), 256, 0, stream>>>(deltaB, aConvB, bc32, A_param,
                                                hend, Pd);
    scan_phaseB2<<<dim3(256), 256, 0, stream>>>(hend, Pd, A_param);
    scan_phaseC<<<dim3(1024), 256, 0, stream>>>(deltaB, aConvB, gateB, bc32,
                                                A_param, D_param, hend, outB);
    // 6) out = ssm_out @ w_out^T  K=512/block -> long-K -> UNR; split-K x4
    gemm_db<64, true><<<dim3(16, 16, 4), 256, 0, stream>>>(outB, 2048, wout_b, 2048,
                                                     part6, 1024, 2097152, 1024, 512,
                                                     nullptr, nullptr, 0);
    out_reduce<<<dim3(2048), 256, 0, stream>>>(part6, out);
}

// Round 7
// 233.020 us; speedup vs baseline: 1.0501x; 1.0111x over previous
//
#include <hip/hip_runtime.h>
#include <math.h>

#define B_SZ 2
#define LSEQ 1024
#define D_INP 1024
#define D_MODEL 2048
#define D_STATE 16
#define D_DISCR 128
#define MROWS (B_SZ * LSEQ)
#define NCH 64
#define CH 16

typedef __bf16 bf16x8 __attribute__((ext_vector_type(8)));
typedef float f32x4 __attribute__((ext_vector_type(4)));
typedef unsigned short ushort8 __attribute__((ext_vector_type(8)));

__device__ __forceinline__ float siluf(float x) { return x / (1.f + expf(-x)); }
__device__ __forceinline__ float softplusf(float x) {
    return fmaxf(x, 0.f) + log1pf(expf(-fabsf(x)));
}
__device__ __forceinline__ unsigned short f2b(float f) {
    unsigned u = __builtin_bit_cast(unsigned, f);
    u = u + 0x7fffu + ((u >> 16) & 1u);
    return (unsigned short)(u >> 16);
}
__device__ __forceinline__ float b2f(unsigned short u) {
    return __builtin_bit_cast(float, ((unsigned)u) << 16);
}

// ---------------------------------------------------------------------------
__global__ __launch_bounds__(256) void cast_all(
    const float* __restrict__ seq, const float* __restrict__ w_in,
    const float* __restrict__ w_out, const float* __restrict__ w_B,
    const float* __restrict__ w_C, const float* __restrict__ w_D1,
    const float* __restrict__ w_D2,
    unsigned short* __restrict__ seq_b, unsigned short* __restrict__ win_b,
    unsigned short* __restrict__ wout_b, unsigned short* __restrict__ wbcd_b,
    unsigned short* __restrict__ wd2_b)
{
    int i = blockIdx.x * 256 + threadIdx.x;
    const float* src; unsigned short* dst; int off;
    if      (i < 262144)  { src = seq;  dst = seq_b;          off = i; }
    else if (i < 786432)  { src = w_in; dst = win_b;          off = i - 262144; }
    else if (i < 1048576) { src = w_out; dst = wout_b;        off = i - 786432; }
    else if (i < 1052672) { src = w_B;  dst = wbcd_b;         off = i - 1048576; }
    else if (i < 1056768) { src = w_C;  dst = wbcd_b + 32768; off = i - 1052672; }
    else if (i < 1089536) { src = w_D1; dst = wbcd_b + 65536; off = i - 1056768; }
    else if (i < 1122304) { src = w_D2; dst = wd2_b;          off = i - 1089536; }
    else return;
    const float4* p = (const float4*)(src + (size_t)off * 8);
    float4 a = p[0], b = p[1];
    ushort8 o = {f2b(a.x), f2b(a.y), f2b(a.z), f2b(a.w),
                 f2b(b.x), f2b(b.y), f2b(b.z), f2b(b.w)};
    *(ushort8*)(dst + (size_t)off * 8) = o;
}

// ---------------------------------------------------------------------------
// bf16 MFMA GEMM-NT — R12/R17 structure: 128xTN tile, BK=32, VGPR-staged
// single-slab prefetch double buffer, 1 barrier/K-iter, XOR-swizzled
// unpadded LDS (0 conflicts). R20: loop flavor per call site (UNR=true:
// compile-time buffer index, long-K; UNR=false: runtime buf, short-K).
// R20 post-mortem: kernel is latency/barrier-bound, not VALU-bound.
// Sweep: 128x64 @4/CU = 41 (R12); 64x64 = 51 (R14); depth-2 = 54 (R11);
// gll = neutral (R13); padded = 71 (R6); 128x128 @2/CU = 85 (R16);
// A-via-registers = 51.5 (R18); short-K pinned unroll = 75.6 (R19).
// Block does K-chunk [z*K, z*K+K) -> Cbase + z*partStride.
// B rows past N read unguarded (must be allocated); masked at store.
// epi: 0 fp32 store; 2 softplus(bias[col]+acc) -> bf16 (Cbase as u16);
//      5 split both-bf16: col<2048 -> (u16*)Cbase, col>=2048 -> C2.
template <int TN, bool UNR>
__global__ __launch_bounds__(256) void gemm_db(
    const unsigned short* __restrict__ A, int lda,
    const unsigned short* __restrict__ B, int ldb,
    float* __restrict__ Cbase, int ldc, size_t partStride,
    int N, int K, const float* __restrict__ bias,
    unsigned short* __restrict__ C2, int epi)
{
    __shared__ unsigned short As[2][128 * 32];
    __shared__ unsigned short Bs[2][TN * 32];
    const int t = threadIdx.x;
    const int w = t >> 6, lane = t & 63;
    const int fr = lane & 15, fq = lane >> 4;
    const int row0 = blockIdx.y * 128, col0 = blockIdx.x * TN;
    const int kz = blockIdx.z * K;
    const int sr = t >> 2, sq = t & 3;
    const int sqz = sq ^ ((sr >> 1) & 3);      // swizzled store chunk
    const int qa = fq ^ ((fr >> 1) & 3);       // swizzled read chunk

    constexpr int NI = (TN == 128) ? 4 : 2;
    const int rbase = (TN == 128) ? (w >> 1) * 64 : w * 32;
    const int cbase = (TN == 128) ? (w & 1) * 64 : 0;

    const unsigned short* gA0 = A + (size_t)(row0 + sr) * lda + kz + sq * 8;
    const unsigned short* gA1 = gA0 + (size_t)64 * lda;
    const unsigned short* gB0 = B + (size_t)(col0 + sr) * ldb + kz + sq * 8;
    const unsigned short* gB1 = gB0 + (size_t)64 * ldb;

    f32x4 acc[NI][4];
#pragma unroll
    for (int i = 0; i < NI; i++)
#pragma unroll
        for (int j = 0; j < 4; j++) acc[i][j] = (f32x4){0.f, 0.f, 0.f, 0.f};

    // prologue: stage slab 0 into buffer 0
    ushort8 a0 = *(const ushort8*)gA0;
    ushort8 a1 = *(const ushort8*)gA1;
    ushort8 b0 = *(const ushort8*)gB0;
    ushort8 b1;
    if (TN == 128) b1 = *(const ushort8*)gB1;
    *(ushort8*)&As[0][sr * 32 + sqz * 8] = a0;
    *(ushort8*)&As[0][(64 + sr) * 32 + sqz * 8] = a1;
    *(ushort8*)&Bs[0][sr * 32 + sqz * 8] = b0;
    if (TN == 128) *(ushort8*)&Bs[0][(64 + sr) * 32 + sqz * 8] = b1;
    __syncthreads();

    if constexpr (UNR) {
        const int nhalf = K / 32;              // even at all UNR call sites
#pragma unroll 1
        for (int p = 0; p < nhalf; p += 2) {
#pragma unroll
            for (int h = 0; h < 2; ++h) {      // h = compile-time buffer idx
                const int k0 = (p + h) * 32;
                const bool more = (k0 + 32 < K);
                if (more) {                    // next-slab loads in flight
                    gA0 += 32; gA1 += 32; gB0 += 32; gB1 += 32;
                    a0 = *(const ushort8*)gA0;
                    a1 = *(const ushort8*)gA1;
                    b0 = *(const ushort8*)gB0;
                    if (TN == 128) b1 = *(const ushort8*)gB1;
                }
                bf16x8 af[NI], bfr[4];
#pragma unroll
                for (int i = 0; i < NI; i++) {
                    ushort8 u = *(const ushort8*)&As[h][(rbase + i * 16 + fr) * 32 + qa * 8];
                    af[i] = __builtin_bit_cast(bf16x8, u);
                }
#pragma unroll
                for (int j = 0; j < 4; j++) {
                    ushort8 u = *(const ushort8*)&Bs[h][(cbase + j * 16 + fr) * 32 + qa * 8];
                    bfr[j] = __builtin_bit_cast(bf16x8, u);
                }
#pragma unroll
                for (int i = 0; i < NI; i++)
#pragma unroll
                    for (int j = 0; j < 4; j++)
                        acc[i][j] = __builtin_amdgcn_mfma_f32_16x16x32_bf16(
                            af[i], bfr[j], acc[i][j], 0, 0, 0);
                if (more) {                    // vmcnt wait lands here, post-MFMA
                    *(ushort8*)&As[h ^ 1][sr * 32 + sqz * 8] = a0;
                    *(ushort8*)&As[h ^ 1][(64 + sr) * 32 + sqz * 8] = a1;
                    *(ushort8*)&Bs[h ^ 1][sr * 32 + sqz * 8] = b0;
                    if (TN == 128) *(ushort8*)&Bs[h ^ 1][(64 + sr) * 32 + sqz * 8] = b1;
                    __syncthreads();
                }
            }
        }
    } else {
        int buf = 0;
        for (int k0 = 0; k0 < K; k0 += 32) {
            const bool more = (k0 + 32 < K);
            if (more) {                        // next-slab loads in flight
                gA0 += 32; gA1 += 32; gB0 += 32; gB1 += 32;
                a0 = *(const ushort8*)gA0;
                a1 = *(const ushort8*)gA1;
                b0 = *(const ushort8*)gB0;
                if (TN == 128) b1 = *(const ushort8*)gB1;
            }
            bf16x8 af[NI], bfr[4];
#pragma unroll
            for (int i = 0; i < NI; i++) {
                ushort8 u = *(const ushort8*)&As[buf][(rbase + i * 16 + fr) * 32 + qa * 8];
                af[i] = __builtin_bit_cast(bf16x8, u);
            }
#pragma unroll
            for (int j = 0; j < 4; j++) {
                ushort8 u = *(const ushort8*)&Bs[buf][(cbase + j * 16 + fr) * 32 + qa * 8];
                bfr[j] = __builtin_bit_cast(bf16x8, u);
            }
#pragma unroll
            for (int i = 0; i < NI; i++)
#pragma unroll
                for (int j = 0; j < 4; j++)
                    acc[i][j] = __builtin_amdgcn_mfma_f32_16x16x32_bf16(
                        af[i], bfr[j], acc[i][j], 0, 0, 0);
            if (more) {
                int nb = buf ^ 1;              // vmcnt wait lands here, post-MFMA
                *(ushort8*)&As[nb][sr * 32 + sqz * 8] = a0;
                *(ushort8*)&As[nb][(64 + sr) * 32 + sqz * 8] = a1;
                *(ushort8*)&Bs[nb][sr * 32 + sqz * 8] = b0;
                if (TN == 128) *(ushort8*)&Bs[nb][(64 + sr) * 32 + sqz * 8] = b1;
                __syncthreads();
                buf = nb;
            }
        }
    }

    float* C = Cbase + (size_t)blockIdx.z * partStride;
#pragma unroll
    for (int i = 0; i < NI; i++) {
#pragma unroll
        for (int r = 0; r < 4; r++) {
            int row = row0 + rbase + i * 16 + fq * 4 + r;
#pragma unroll
            for (int j = 0; j < 4; j++) {   // j-inner: contiguous write runs
                int col = col0 + cbase + j * 16 + fr;
                if (col >= N) continue;
                float v = acc[i][j][r];
                if (epi == 0) C[(size_t)row * ldc + col] = v;
                else if (epi == 2)
                    ((unsigned short*)Cbase)[(size_t)row * ldc + col] =
                        f2b(softplusf(bias[col] + v));
                else {
                    unsigned short v16 = f2b(v);
                    if (col < 2048) ((unsigned short*)Cbase)[(size_t)row * 2048 + col] = v16;
                    else C2[(size_t)row * 2048 + col - 2048] = v16;
                }
            }
        }
    }
}

// ---------------------------------------------------------------------------
// R22: gemm1 with BK=64 — one barrier per 64 K (16 total vs 32). A 64-wide
// K-step = two existing BK=32 sub-slabs (same swizzle math per sub) staged
// back-to-back into [2][2] LDS; all 6 next-step loads issued before the
// MFMA block (max MLP), ONE barrier per step. LDS 48 KB -> 3 blocks/CU
// (12 waves/CU vs 16). Tests the "untested axis" from the R12 sweep:
// barrier-drain amortization vs occupancy. TN=64 wave layout (rbase=w*32),
// N=4096 full tile (no masking), epi-5 split store (aB / gateB).
__global__ __launch_bounds__(256) void gemm1_bk64(
    const unsigned short* __restrict__ A, int lda,
    const unsigned short* __restrict__ B, int ldb,
    unsigned short* __restrict__ Cb, unsigned short* __restrict__ C2, int K)
{
    __shared__ unsigned short As[2][2][128 * 32];
    __shared__ unsigned short Bs[2][2][64 * 32];
    const int t = threadIdx.x;
    const int w = t >> 6, lane = t & 63;
    const int fr = lane & 15, fq = lane >> 4;
    const int row0 = blockIdx.y * 128, col0 = blockIdx.x * 64;
    const int sr = t >> 2, sq = t & 3;
    const int sqz = sq ^ ((sr >> 1) & 3);
    const int qa = fq ^ ((fr >> 1) & 3);
    const int rbase = w * 32;

    const unsigned short* gA0 = A + (size_t)(row0 + sr) * lda + sq * 8;
    const unsigned short* gA1 = gA0 + (size_t)64 * lda;
    const unsigned short* gB0 = B + (size_t)(col0 + sr) * ldb + sq * 8;

    f32x4 acc[2][4];
#pragma unroll
    for (int i = 0; i < 2; i++)
#pragma unroll
        for (int j = 0; j < 4; j++) acc[i][j] = (f32x4){0.f, 0.f, 0.f, 0.f};

    // prologue: stage K-step 0 (both 32-wide subs) into phase 0
    ushort8 a0 = *(const ushort8*)gA0;
    ushort8 a1 = *(const ushort8*)gA1;
    ushort8 b0 = *(const ushort8*)gB0;
    ushort8 a0b = *(const ushort8*)(gA0 + 32);
    ushort8 a1b = *(const ushort8*)(gA1 + 32);
    ushort8 b0b = *(const ushort8*)(gB0 + 32);
    *(ushort8*)&As[0][0][sr * 32 + sqz * 8] = a0;
    *(ushort8*)&As[0][0][(64 + sr) * 32 + sqz * 8] = a1;
    *(ushort8*)&Bs[0][0][sr * 32 + sqz * 8] = b0;
    *(ushort8*)&As[0][1][sr * 32 + sqz * 8] = a0b;
    *(ushort8*)&As[0][1][(64 + sr) * 32 + sqz * 8] = a1b;
    *(ushort8*)&Bs[0][1][sr * 32 + sqz * 8] = b0b;
    __syncthreads();

    const int nstep = K / 64;                  // 16
#pragma unroll 1
    for (int p = 0; p < nstep; p += 2) {
#pragma unroll
        for (int h = 0; h < 2; ++h) {          // h = compile-time phase idx
            const int k0 = (p + h) * 64;
            const bool more = (k0 + 64 < K);
            if (more) {                        // 6 next-step loads in flight
                gA0 += 64; gA1 += 64; gB0 += 64;
                a0 = *(const ushort8*)gA0;
                a1 = *(const ushort8*)gA1;
                b0 = *(const ushort8*)gB0;
                a0b = *(const ushort8*)(gA0 + 32);
                a1b = *(const ushort8*)(gA1 + 32);
                b0b = *(const ushort8*)(gB0 + 32);
            }
            bf16x8 af0[2], af1[2], bf0[4], bf1[4];
#pragma unroll
            for (int i = 0; i < 2; i++) {
                ushort8 u0 = *(const ushort8*)&As[h][0][(rbase + i * 16 + fr) * 32 + qa * 8];
                ushort8 u1 = *(const ushort8*)&As[h][1][(rbase + i * 16 + fr) * 32 + qa * 8];
                af0[i] = __builtin_bit_cast(bf16x8, u0);
                af1[i] = __builtin_bit_cast(bf16x8, u1);
            }
#pragma unroll
            for (int j = 0; j < 4; j++) {
                ushort8 u0 = *(const ushort8*)&Bs[h][0][(j * 16 + fr) * 32 + qa * 8];
                ushort8 u1 = *(const ushort8*)&Bs[h][1][(j * 16 + fr) * 32 + qa * 8];
                bf0[j] = __builtin_bit_cast(bf16x8, u0);
                bf1[j] = __builtin_bit_cast(bf16x8, u1);
            }
#pragma unroll
            for (int i = 0; i < 2; i++)
#pragma unroll
                for (int j = 0; j < 4; j++) {
                    acc[i][j] = __builtin_amdgcn_mfma_f32_16x16x32_bf16(
                        af0[i], bf0[j], acc[i][j], 0, 0, 0);
                    acc[i][j] = __builtin_amdgcn_mfma_f32_16x16x32_bf16(
                        af1[i], bf1[j], acc[i][j], 0, 0, 0);
                }
            if (more) {                        // vmcnt wait lands here, post-MFMA
                *(ushort8*)&As[h ^ 1][0][sr * 32 + sqz * 8] = a0;
                *(ushort8*)&As[h ^ 1][0][(64 + sr) * 32 + sqz * 8] = a1;
                *(ushort8*)&Bs[h ^ 1][0][sr * 32 + sqz * 8] = b0;
                *(ushort8*)&As[h ^ 1][1][sr * 32 + sqz * 8] = a0b;
                *(ushort8*)&As[h ^ 1][1][(64 + sr) * 32 + sqz * 8] = a1b;
                *(ushort8*)&Bs[h ^ 1][1][sr * 32 + sqz * 8] = b0b;
                __syncthreads();
            }
        }
    }

#pragma unroll
    for (int i = 0; i < 2; i++) {
#pragma unroll
        for (int r = 0; r < 4; r++) {
            int row = row0 + rbase + i * 16 + fq * 4 + r;
#pragma unroll
            for (int j = 0; j < 4; j++) {
                int col = col0 + j * 16 + fr;
                unsigned short v16 = f2b(acc[i][j][r]);
                if (col < 2048) Cb[(size_t)row * 2048 + col] = v16;
                else C2[(size_t)row * 2048 + col - 2048] = v16;
            }
        }
    }
}

// ---------------------------------------------------------------------------
// R21: dedicated delta GEMM (gemm4): K=128 whole-K in LDS, ONE barrier.
// Evidence (R19): looped form at 4 K-iters was pure latency (MfmaUtil 0.5%).
__global__ __launch_bounds__(256) void gemm_d4(
    const unsigned short* __restrict__ A,   // bcdB+32, lda=160
    const unsigned short* __restrict__ B,   // wd2_b,  ldb=128
    unsigned short* __restrict__ Cb,        // deltaB (u16), ldc=2048
    const float* __restrict__ bias)
{
    __shared__ unsigned short As[4][128 * 32];
    __shared__ unsigned short Bs[4][64 * 32];
    const int t = threadIdx.x;
    const int w = t >> 6, lane = t & 63;
    const int fr = lane & 15, fq = lane >> 4;
    const int row0 = blockIdx.y * 128, col0 = blockIdx.x * 64;
    const int sr = t >> 2, sq = t & 3;
    const int sqz = sq ^ ((sr >> 1) & 3);
    const int qa = fq ^ ((fr >> 1) & 3);
    const int rbase = w * 32;

    ushort8 a0[4], a1[4], b0[4];
#pragma unroll
    for (int s = 0; s < 4; s++) {
        a0[s] = *(const ushort8*)(A + (size_t)(row0 + sr) * 160 + s * 32 + sq * 8);
        a1[s] = *(const ushort8*)(A + (size_t)(row0 + 64 + sr) * 160 + s * 32 + sq * 8);
        b0[s] = *(const ushort8*)(B + (size_t)(col0 + sr) * 128 + s * 32 + sq * 8);
    }
#pragma unroll
    for (int s = 0; s < 4; s++) {
        *(ushort8*)&As[s][sr * 32 + sqz * 8] = a0[s];
        *(ushort8*)&As[s][(64 + sr) * 32 + sqz * 8] = a1[s];
        *(ushort8*)&Bs[s][sr * 32 + sqz * 8] = b0[s];
    }
    __syncthreads();

    f32x4 acc[2][4];
#pragma unroll
    for (int i = 0; i < 2; i++)
#pragma unroll
        for (int j = 0; j < 4; j++) acc[i][j] = (f32x4){0.f, 0.f, 0.f, 0.f};

#pragma unroll
    for (int s = 0; s < 4; s++) {
        bf16x8 af[2], bfr[4];
#pragma unroll
        for (int i = 0; i < 2; i++) {
            ushort8 u = *(const ushort8*)&As[s][(rbase + i * 16 + fr) * 32 + qa * 8];
            af[i] = __builtin_bit_cast(bf16x8, u);
        }
#pragma unroll
        for (int j = 0; j < 4; j++) {
            ushort8 u = *(const ushort8*)&Bs[s][(j * 16 + fr) * 32 + qa * 8];
            bfr[j] = __builtin_bit_cast(bf16x8, u);
        }
#pragma unroll
        for (int i = 0; i < 2; i++)
#pragma unroll
            for (int j = 0; j < 4; j++)
                acc[i][j] = __builtin_amdgcn_mfma_f32_16x16x32_bf16(
                    af[i], bfr[j], acc[i][j], 0, 0, 0);
    }

#pragma unroll
    for (int i = 0; i < 2; i++) {
#pragma unroll
        for (int r = 0; r < 4; r++) {
            int row = row0 + rbase + i * 16 + fq * 4 + r;
#pragma unroll
            for (int j = 0; j < 4; j++) {
                int col = col0 + j * 16 + fr;
                Cb[(size_t)row * 2048 + col] =
                    f2b(softplusf(bias[col] + acc[i][j][r]));
            }
        }
    }
}

// ---------------------------------------------------------------------------
__global__ __launch_bounds__(256) void bcd_reduce(
    const float* __restrict__ part, unsigned short* __restrict__ bcdB,
    float* __restrict__ bc32)
{
    int t = blockIdx.x * 256 + threadIdx.x;
    if (t >= 327680) return;
    float s = 0.f;
#pragma unroll
    for (int z = 0; z < 8; z++) s += part[(size_t)z * 327680 + t];
    bcdB[t] = f2b(s);
    int col = t % 160;
    if (col < 32) bc32[(size_t)(t / 160) * 32 + col] = s;
}

// sum 4 split-K partials of gemm6 -> final out
__global__ __launch_bounds__(256) void out_reduce(
    const float* __restrict__ part, float* __restrict__ out)
{
    int i = blockIdx.x * 256 + threadIdx.x;    // 524288 float4 groups
    float4 p0 = ((const float4*)part)[i];
    float4 p1 = ((const float4*)(part + 2097152))[i];
    float4 p2 = ((const float4*)(part + 4194304))[i];
    float4 p3 = ((const float4*)(part + 6291456))[i];
    float4 o = {p0.x + p1.x + p2.x + p3.x, p0.y + p1.y + p2.y + p3.y,
                p0.z + p1.z + p2.z + p3.z, p0.w + p1.w + p2.w + p3.w};
    ((float4*)out)[i] = o;
}

// ---------------------------------------------------------------------------
// depthwise causal conv1d (K=4) + bias + SiLU; bf16 in/out, 8 d's per thread.
// R16 (verified): rolling window over 4 consecutive l per thread.
__global__ __launch_bounds__(256) void conv_silu8(
    const unsigned short* __restrict__ aB,
    const float* __restrict__ cw, const float* __restrict__ cb,
    unsigned short* __restrict__ aConvB)
{
    int blk = blockIdx.x;                      // 512 = b*256 + lg
    int lg = blk & 255, b = blk >> 8;
    int l0 = lg << 2;
    int d8 = threadIdx.x << 3;
    const unsigned short* base = aB + (size_t)(b * LSEQ + l0) * 2048 + d8;
    unsigned short* obase = aConvB + (size_t)(b * LSEQ + l0) * 2048 + d8;
    const ushort8 z8 = {0, 0, 0, 0, 0, 0, 0, 0};
    ushort8 xm3, xm2, xm1;
    if (l0 > 0) {                              // l0 multiple of 4 -> l0>=3
        xm3 = *(const ushort8*)(base - 3 * 2048);
        xm2 = *(const ushort8*)(base - 2 * 2048);
        xm1 = *(const ushort8*)(base - 1 * 2048);
    } else { xm3 = z8; xm2 = z8; xm1 = z8; }
    float4 cb0 = *(const float4*)(cb + d8);
    float4 cb1 = *(const float4*)(cb + d8 + 4);
    float bv[8] = {cb0.x, cb0.y, cb0.z, cb0.w, cb1.x, cb1.y, cb1.z, cb1.w};
    float4 w0[8];
#pragma unroll
    for (int j = 0; j < 8; j++) w0[j] = *(const float4*)(cw + (size_t)(d8 + j) * 4);
#pragma unroll
    for (int t = 0; t < 4; t++) {
        ushort8 x0 = *(const ushort8*)(base + t * 2048);
        ushort8 o;
#pragma unroll
        for (int j = 0; j < 8; j++) {
            float acc = bv[j];
            acc = fmaf(b2f(x0[j]),  w0[j].w, acc);
            acc = fmaf(b2f(xm1[j]), w0[j].z, acc);
            acc = fmaf(b2f(xm2[j]), w0[j].y, acc);
            acc = fmaf(b2f(xm3[j]), w0[j].x, acc);
            o[j] = f2b(siluf(acc));
        }
        *(ushort8*)(obase + t * 2048) = o;
        xm3 = xm2; xm2 = xm1; xm1 = x0;
    }
}

// ---------------------------------------------------------------------------
// Chunk-parallel scan, 64 chunks x 16 steps, bf16 inputs (fp32 compute,
// fp32 hend). hend idx(b,c,s,d) = (((b*64+c)*16+s)<<11)+d.
__global__ __launch_bounds__(256) void scan_phaseA(
    const unsigned short* __restrict__ deltaB,
    const unsigned short* __restrict__ aConvB,
    const float* __restrict__ bc32, const float* __restrict__ A_param,
    float* __restrict__ hend, float* __restrict__ Pd)
{
    int blk = blockIdx.x;                      // 1024
    int d = ((blk & 7) << 8) + threadIdx.x;
    int c = (blk >> 3) & 63;
    int b = blk >> 9;
    float expA[16], h[16];
#pragma unroll
    for (int s = 0; s < 16; s++) {
        expA[s] = expf(-A_param[d * 16 + s]);
        h[s] = 0.f;
    }
    float P = 1.f;
    int r0 = b * LSEQ + c * CH;
    const unsigned short* dp = deltaB + (size_t)r0 * D_MODEL + d;
    const unsigned short* ap = aConvB + (size_t)r0 * D_MODEL + d;
    const float4* bp = (const float4*)(bc32 + (size_t)r0 * 32);
    float dlt = b2f(*dp), av = b2f(*ap);
    float4 B0 = bp[0], B1 = bp[1], B2 = bp[2], B3 = bp[3];
    for (int l = 0; l < CH; l++) {
        dp += 2048; ap += 2048; bp += 8;       // prefetch l+1 (lands in ws, safe)
        float nd = b2f(*dp), na = b2f(*ap);
        float4 nB0 = bp[0], nB1 = bp[1], nB2 = bp[2], nB3 = bp[3];
        float Bv[16] = {B0.x, B0.y, B0.z, B0.w, B1.x, B1.y, B1.z, B1.w,
                        B2.x, B2.y, B2.z, B2.w, B3.x, B3.y, B3.z, B3.w};
        float x = dlt * av;
        P *= dlt;
#pragma unroll
        for (int s = 0; s < 16; s++)
            h[s] = fmaf(expA[s] * dlt, h[s], Bv[s] * x);
        dlt = nd; av = na; B0 = nB0; B1 = nB1; B2 = nB2; B3 = nB3;
    }
    size_t base = (((size_t)(b * 64 + c) * 16) << 11) + d;
#pragma unroll
    for (int s = 0; s < 16; s++)
        hend[base + ((size_t)s << 11)] = h[s];
    Pd[(size_t)(b * 64 + c) * 2048 + d] = P;
}

// chunk prefix: overwrite hend[c] with state ENTERING chunk c.
// R16 (verified): depth-4 software prefetch. All register names static.
__global__ __launch_bounds__(256) void scan_phaseB2(
    float* __restrict__ hend, const float* __restrict__ Pd,
    const float* __restrict__ A_param)
{
    int t = blockIdx.x * 256 + threadIdx.x;    // 65536
    int d = t & 2047, s = (t >> 11) & 15, b = t >> 15;
    float e = expf(-A_param[d * 16 + s]);
    float e2 = e * e, e4 = e2 * e2, e8 = e4 * e4;
    float eCH = e8 * e8;                       // expA^16
    size_t idx = (((size_t)(b * 64) * 16 + s) << 11) + d;
    const size_t cs = (size_t)16 << 11;
    size_t pidx = (size_t)(b * 64) * 2048 + d;
    float h = 0.f;
    float he0 = hend[idx], he1 = hend[idx + cs];
    float he2 = hend[idx + 2 * cs], he3 = hend[idx + 3 * cs];
    float P0 = Pd[pidx], P1 = Pd[pidx + 2048];
    float P2 = Pd[pidx + 2 * 2048], P3 = Pd[pidx + 3 * 2048];
    for (int c = 0; c < NCH; c += 4) {
        size_t idx4 = idx + 4 * cs;
        size_t pidx4 = pidx + (size_t)4 * 2048;
        float nh0 = 0.f, nh1 = 0.f, nh2 = 0.f, nh3 = 0.f;
        float nP0 = 0.f, nP1 = 0.f, nP2 = 0.f, nP3 = 0.f;
        if (c + 4 < NCH) {
            nh0 = hend[idx4];          nh1 = hend[idx4 + cs];
            nh2 = hend[idx4 + 2 * cs]; nh3 = hend[idx4 + 3 * cs];
            nP0 = Pd[pidx4];           nP1 = Pd[pidx4 + 2048];
            nP2 = Pd[pidx4 + 2 * 2048]; nP3 = Pd[pidx4 + 3 * 2048];
        }
        hend[idx] = h;            h = fmaf(eCH * P0, h, he0);
        hend[idx + cs] = h;       h = fmaf(eCH * P1, h, he1);
        hend[idx + 2 * cs] = h;   h = fmaf(eCH * P2, h, he2);
        hend[idx + 3 * cs] = h;   h = fmaf(eCH * P3, h, he3);
        idx = idx4; pidx = pidx4;
        he0 = nh0; he1 = nh1; he2 = nh2; he3 = nh3;
        P0 = nP0; P1 = nP1; P2 = nP2; P3 = nP3;
    }
}

__global__ __launch_bounds__(256) void scan_phaseC(
    const unsigned short* __restrict__ deltaB,
    const unsigned short* __restrict__ aConvB,
    const unsigned short* __restrict__ gateB,
    const float* __restrict__ bc32,
    const float* __restrict__ A_param, const float* __restrict__ D_param,
    const float* __restrict__ hend, unsigned short* __restrict__ outB)
{
    int blk = blockIdx.x;                      // 1024
    int d = ((blk & 7) << 8) + threadIdx.x;
    int c = (blk >> 3) & 63;
    int b = blk >> 9;
    float expA[16], h[16];
    size_t base = (((size_t)(b * 64 + c) * 16) << 11) + d;
#pragma unroll
    for (int s = 0; s < 16; s++) {
        expA[s] = expf(-A_param[d * 16 + s]);
        h[s] = hend[base + ((size_t)s << 11)];
    }
    float Dp = D_param[d];
    int r0 = b * LSEQ + c * CH;
    const unsigned short* dp = deltaB + (size_t)r0 * D_MODEL + d;
    const unsigned short* ap = aConvB + (size_t)r0 * D_MODEL + d;
    const unsigned short* gp = gateB + (size_t)r0 * 2048 + d;
    const float4* bp = (const float4*)(bc32 + (size_t)r0 * 32);
    unsigned short* op = outB + (size_t)r0 * D_MODEL + d;
    float dlt = b2f(*dp), av = b2f(*ap), g = b2f(*gp);
    float4 B0 = bp[0], B1 = bp[1], B2 = bp[2], B3 = bp[3];
    float4 C0 = bp[4], C1 = bp[5], C2 = bp[6], C3 = bp[7];
    for (int l = 0; l < CH; l++) {
        dp += 2048; ap += 2048; gp += 2048; bp += 8;
        float nd = b2f(*dp), na = b2f(*ap), ng = b2f(*gp);
        float4 nB0 = bp[0], nB1 = bp[1], nB2 = bp[2], nB3 = bp[3];
        float4 nC0 = bp[4], nC1 = bp[5], nC2 = bp[6], nC3 = bp[7];
        float Bv[16] = {B0.x, B0.y, B0.z, B0.w, B1.x, B1.y, B1.z, B1.w,
                        B2.x, B2.y, B2.z, B2.w, B3.x, B3.y, B3.z, B3.w};
        float Cv[16] = {C0.x, C0.y, C0.z, C0.w, C1.x, C1.y, C1.z, C1.w,
                        C2.x, C2.y, C2.z, C2.w, C3.x, C3.y, C3.z, C3.w};
        float x = dlt * av;
        float acc = 0.f;
#pragma unroll
        for (int s = 0; s < 16; s++) {
            float Ab = expA[s] * dlt;
            h[s] = fmaf(Ab, h[s], Bv[s] * x);
            acc = fmaf(h[s], Cv[s], acc);
        }
        *op = f2b((acc + Dp * av) * siluf(g));
        op += D_MODEL;
        dlt = nd; av = na; g = ng;
        B0 = nB0; B1 = nB1; B2 = nB2; B3 = nB3;
        C0 = nC0; C1 = nC1; C2 = nC2; C3 = nC3;
    }
}

extern "C" void kernel_launch(void* const* d_in, const int* in_sizes, int n_in,
                              void* d_out, int out_size, void* d_ws, size_t ws_size,
                              hipStream_t stream) {
    const float* seq = (const float*)d_in[0];
    const float* w_in = (const float*)d_in[1];
    const float* w_out = (const float*)d_in[2];
    const float* w_B = (const float*)d_in[3];
    const float* w_C = (const float*)d_in[4];
    const float* w_D1 = (const float*)d_in[5];
    const float* w_D2 = (const float*)d_in[6];
    const float* conv_w = (const float*)d_in[7];
    const float* conv_b = (const float*)d_in[8];
    const float* A_param = (const float*)d_in[9];
    const float* D_param = (const float*)d_in[10];
    float* out = (float*)d_out;

    // fp32 region (floats)
    float* bc32  = (float*)d_ws;                   // 65,536
    float* part  = bc32 + (size_t)65536;           // 2,621,440 (dead after reduce)
    float* part6 = part + (size_t)2621440;         // 8,388,608 (gemm6 partials)
    float* Pd    = part;                           // overlay: 262,144 ✓ (part dead)
    float* hend  = part6;                          // overlay: 4,194,304 ✓ (hend dead
                                                   //  before gemm6 writes part6)
    // bf16 region
    unsigned short* seq_b  = (unsigned short*)(part6 + 8388608);
    unsigned short* win_b  = seq_b + (size_t)2097152;
    unsigned short* wout_b = win_b + (size_t)4194304;
    unsigned short* wbcd_b = wout_b + (size_t)2097152;  // [160,2048]
    unsigned short* wd2_b  = wbcd_b + (size_t)327680;   // [2048,128]
    unsigned short* aB     = wd2_b + (size_t)262144;    // [2048,2048]
    unsigned short* aConvB = aB + (size_t)4194304;      // [2048,2048]
    unsigned short* deltaB = aConvB + (size_t)4194304;  // [2048,2048]
    unsigned short* gateB  = deltaB + (size_t)4194304;  // [2048,2048]
    unsigned short* outB   = gateB + (size_t)4194304;   // [2048,2048]
    unsigned short* bcdB   = outB + (size_t)4194304;    // [2048,160]

    // 0) casts
    cast_all<<<dim3(4384), 256, 0, stream>>>(seq, w_in, w_out, w_B, w_C, w_D1, w_D2,
                                             seq_b, win_b, wout_b, wbcd_b, wd2_b);
    // 1) [a|gate] = seq @ w_in^T  [2048 x 4096] K=1024; R22: BK=64 variant
    gemm1_bk64<<<dim3(64, 16), 256, 0, stream>>>(seq_b, 1024, win_b, 1024,
                                                 (unsigned short*)aB, gateB, 1024);
    // 2) conv + SiLU (bf16 in/out, 8-wide, 4-l rolling window)
    conv_silu8<<<dim3(512), 256, 0, stream>>>(aB, conv_w, conv_b, aConvB);
    // 3) bcd split-K x8, TN=64, K=256/block -> short-K, runtime-buf loop
    gemm_db<64, false><<<dim3(3, 16, 8), 256, 0, stream>>>(aConvB, 2048, wbcd_b, 2048,
                                                    part, 160, 327680, 160, 256,
                                                    nullptr, nullptr, 0);
    bcd_reduce<<<dim3(1280), 256, 0, stream>>>(part, bcdB, bc32);
    // 4) deltaB = bf16(softplus(D + d1 @ wD2^T))  K=128 -> R21 whole-K kernel
    gemm_d4<<<dim3(32, 16), 256, 0, stream>>>(bcdB + 32, wd2_b,
                                              deltaB, D_param);
    // 5) chunk-parallel scan (64 chunks x 16 steps; bf16 datapath, fp32 hend)
    scan_phaseA<<<dim3(1024), 256, 0, stream>>>(deltaB, aConvB, bc32, A_param,
                                                hend, Pd);
    scan_phaseB2<<<dim3(256), 256, 0, stream>>>(hend, Pd, A_param);
    scan_phaseC<<<dim3(1024), 256, 0, stream>>>(deltaB, aConvB, gateB, bc32,
                                                A_param, D_param, hend, outB);
    // 6) out = ssm_out @ w_out^T  K=512/block -> long-K -> UNR; split-K x4
    gemm_db<64, true><<<dim3(16, 16, 4), 256, 0, stream>>>(outB, 2048, wout_b, 2048,
                                                     part6, 1024, 2097152, 1024, 512,
                                                     nullptr, nullptr, 0);
    out_reduce<<<dim3(2048), 256, 0, stream>>>(part6, out);
}

// Round 8
// 221.113 us; speedup vs baseline: 1.1067x; 1.0538x over previous
//
#include <hip/hip_runtime.h>
#include <math.h>

#define B_SZ 2
#define LSEQ 1024
#define D_INP 1024
#define D_MODEL 2048
#define D_STATE 16
#define D_DISCR 128
#define MROWS (B_SZ * LSEQ)
#define NCH 64
#define CH 16

typedef __bf16 bf16x8 __attribute__((ext_vector_type(8)));
typedef float f32x4 __attribute__((ext_vector_type(4)));
typedef unsigned short ushort8 __attribute__((ext_vector_type(8)));

__device__ __forceinline__ float siluf(float x) { return x / (1.f + expf(-x)); }
__device__ __forceinline__ float softplusf(float x) {
    return fmaxf(x, 0.f) + log1pf(expf(-fabsf(x)));
}
__device__ __forceinline__ unsigned short f2b(float f) {
    unsigned u = __builtin_bit_cast(unsigned, f);
    u = u + 0x7fffu + ((u >> 16) & 1u);
    return (unsigned short)(u >> 16);
}
__device__ __forceinline__ float b2f(unsigned short u) {
    return __builtin_bit_cast(float, ((unsigned)u) << 16);
}

// ---------------------------------------------------------------------------
__global__ __launch_bounds__(256) void cast_all(
    const float* __restrict__ seq, const float* __restrict__ w_in,
    const float* __restrict__ w_out, const float* __restrict__ w_B,
    const float* __restrict__ w_C, const float* __restrict__ w_D1,
    const float* __restrict__ w_D2,
    unsigned short* __restrict__ seq_b, unsigned short* __restrict__ win_b,
    unsigned short* __restrict__ wout_b, unsigned short* __restrict__ wbcd_b,
    unsigned short* __restrict__ wd2_b)
{
    int i = blockIdx.x * 256 + threadIdx.x;
    const float* src; unsigned short* dst; int off;
    if      (i < 262144)  { src = seq;  dst = seq_b;          off = i; }
    else if (i < 786432)  { src = w_in; dst = win_b;          off = i - 262144; }
    else if (i < 1048576) { src = w_out; dst = wout_b;        off = i - 786432; }
    else if (i < 1052672) { src = w_B;  dst = wbcd_b;         off = i - 1048576; }
    else if (i < 1056768) { src = w_C;  dst = wbcd_b + 32768; off = i - 1052672; }
    else if (i < 1089536) { src = w_D1; dst = wbcd_b + 65536; off = i - 1056768; }
    else if (i < 1122304) { src = w_D2; dst = wd2_b;          off = i - 1089536; }
    else return;
    const float4* p = (const float4*)(src + (size_t)off * 8);
    float4 a = p[0], b = p[1];
    ushort8 o = {f2b(a.x), f2b(a.y), f2b(a.z), f2b(a.w),
                 f2b(b.x), f2b(b.y), f2b(b.z), f2b(b.w)};
    *(ushort8*)(dst + (size_t)off * 8) = o;
}

// ---------------------------------------------------------------------------
// bf16 MFMA GEMM-NT — R12/R17 structure: 128xTN tile, BK=32, VGPR-staged
// single-slab prefetch double buffer, 1 barrier/K-iter, XOR-swizzled
// unpadded LDS (0 conflicts). Runtime-buf loop (short-K sites only now):
// R19 showed a pinned unroll at ~4 K-iters destroys the compiler's
// short-pipeline schedule (gemm4 41 -> 75.6 µs). Used for gemm3 (K=256).
// Sweep: 128x64 @4/CU = 41 (R12); 64x64 = 51 (R14); depth-2 = 54 (R11);
// gll = neutral (R13); padded = 71 (R6); 128x128 @2/CU = 85 (R16);
// A-via-registers = 51.5 (R18); BK=64 = win on long-K (R22).
// Block does K-chunk [z*K, z*K+K) -> Cbase + z*partStride.
// B rows past N read unguarded (must be allocated); masked at store.
template <int TN, bool UNR>
__global__ __launch_bounds__(256) void gemm_db(
    const unsigned short* __restrict__ A, int lda,
    const unsigned short* __restrict__ B, int ldb,
    float* __restrict__ Cbase, int ldc, size_t partStride,
    int N, int K, const float* __restrict__ bias,
    unsigned short* __restrict__ C2, int epi)
{
    __shared__ unsigned short As[2][128 * 32];
    __shared__ unsigned short Bs[2][TN * 32];
    const int t = threadIdx.x;
    const int w = t >> 6, lane = t & 63;
    const int fr = lane & 15, fq = lane >> 4;
    const int row0 = blockIdx.y * 128, col0 = blockIdx.x * TN;
    const int kz = blockIdx.z * K;
    const int sr = t >> 2, sq = t & 3;
    const int sqz = sq ^ ((sr >> 1) & 3);      // swizzled store chunk
    const int qa = fq ^ ((fr >> 1) & 3);       // swizzled read chunk

    constexpr int NI = (TN == 128) ? 4 : 2;
    const int rbase = (TN == 128) ? (w >> 1) * 64 : w * 32;
    const int cbase = (TN == 128) ? (w & 1) * 64 : 0;

    const unsigned short* gA0 = A + (size_t)(row0 + sr) * lda + kz + sq * 8;
    const unsigned short* gA1 = gA0 + (size_t)64 * lda;
    const unsigned short* gB0 = B + (size_t)(col0 + sr) * ldb + kz + sq * 8;
    const unsigned short* gB1 = gB0 + (size_t)64 * ldb;

    f32x4 acc[NI][4];
#pragma unroll
    for (int i = 0; i < NI; i++)
#pragma unroll
        for (int j = 0; j < 4; j++) acc[i][j] = (f32x4){0.f, 0.f, 0.f, 0.f};

    // prologue: stage slab 0 into buffer 0
    ushort8 a0 = *(const ushort8*)gA0;
    ushort8 a1 = *(const ushort8*)gA1;
    ushort8 b0 = *(const ushort8*)gB0;
    ushort8 b1;
    if (TN == 128) b1 = *(const ushort8*)gB1;
    *(ushort8*)&As[0][sr * 32 + sqz * 8] = a0;
    *(ushort8*)&As[0][(64 + sr) * 32 + sqz * 8] = a1;
    *(ushort8*)&Bs[0][sr * 32 + sqz * 8] = b0;
    if (TN == 128) *(ushort8*)&Bs[0][(64 + sr) * 32 + sqz * 8] = b1;
    __syncthreads();

    int buf = 0;
    for (int k0 = 0; k0 < K; k0 += 32) {
        const bool more = (k0 + 32 < K);
        if (more) {                        // next-slab loads in flight
            gA0 += 32; gA1 += 32; gB0 += 32; gB1 += 32;
            a0 = *(const ushort8*)gA0;
            a1 = *(const ushort8*)gA1;
            b0 = *(const ushort8*)gB0;
            if (TN == 128) b1 = *(const ushort8*)gB1;
        }
        bf16x8 af[NI], bfr[4];
#pragma unroll
        for (int i = 0; i < NI; i++) {
            ushort8 u = *(const ushort8*)&As[buf][(rbase + i * 16 + fr) * 32 + qa * 8];
            af[i] = __builtin_bit_cast(bf16x8, u);
        }
#pragma unroll
        for (int j = 0; j < 4; j++) {
            ushort8 u = *(const ushort8*)&Bs[buf][(cbase + j * 16 + fr) * 32 + qa * 8];
            bfr[j] = __builtin_bit_cast(bf16x8, u);
        }
#pragma unroll
        for (int i = 0; i < NI; i++)
#pragma unroll
            for (int j = 0; j < 4; j++)
                acc[i][j] = __builtin_amdgcn_mfma_f32_16x16x32_bf16(
                    af[i], bfr[j], acc[i][j], 0, 0, 0);
        if (more) {
            int nb = buf ^ 1;              // vmcnt wait lands here, post-MFMA
            *(ushort8*)&As[nb][sr * 32 + sqz * 8] = a0;
            *(ushort8*)&As[nb][(64 + sr) * 32 + sqz * 8] = a1;
            *(ushort8*)&Bs[nb][sr * 32 + sqz * 8] = b0;
            if (TN == 128) *(ushort8*)&Bs[nb][(64 + sr) * 32 + sqz * 8] = b1;
            __syncthreads();
            buf = nb;
        }
    }

    float* C = Cbase + (size_t)blockIdx.z * partStride;
#pragma unroll
    for (int i = 0; i < NI; i++) {
#pragma unroll
        for (int r = 0; r < 4; r++) {
            int row = row0 + rbase + i * 16 + fq * 4 + r;
#pragma unroll
            for (int j = 0; j < 4; j++) {   // j-inner: contiguous write runs
                int col = col0 + cbase + j * 16 + fr;
                if (col >= N) continue;
                float v = acc[i][j][r];
                if (epi == 0) C[(size_t)row * ldc + col] = v;
                else if (epi == 2)
                    ((unsigned short*)Cbase)[(size_t)row * ldc + col] =
                        f2b(softplusf(bias[col] + v));
                else {
                    unsigned short v16 = f2b(v);
                    if (col < 2048) ((unsigned short*)Cbase)[(size_t)row * 2048 + col] = v16;
                    else C2[(size_t)row * 2048 + col - 2048] = v16;
                }
            }
        }
    }
}

// ---------------------------------------------------------------------------
// R22/R23: BK=64 long-K GEMM — one barrier per 64 K. A 64-wide K-step =
// two BK=32 sub-slabs (same swizzle math per sub) staged into [2][2] LDS;
// all 6 next-step loads issued before the MFMA block, ONE barrier/step.
// LDS 48 KB -> 3 blocks/CU (12 waves/CU). R22 on gemm1: 41 -> ~38 µs
// (barrier amortization beat the occupancy loss). R23 generalizes to
// split-K (kz = z*K) + EPI and applies it to gemm6 (K=512/block).
// Both call sites have full tiles (gemm1 N=4096, gemm6 N=1024) — no
// store masking. EPI: 0 = fp32 partial store to Cbase + z*partStride;
// 5 = split bf16 store (col<2048 -> Cb, else C2).
template <int EPI>
__global__ __launch_bounds__(256) void gemm_bk64(
    const unsigned short* __restrict__ A, int lda,
    const unsigned short* __restrict__ B, int ldb,
    float* __restrict__ Cbase, int ldc, size_t partStride,
    int K, unsigned short* __restrict__ C2)
{
    __shared__ unsigned short As[2][2][128 * 32];
    __shared__ unsigned short Bs[2][2][64 * 32];
    const int t = threadIdx.x;
    const int w = t >> 6, lane = t & 63;
    const int fr = lane & 15, fq = lane >> 4;
    const int row0 = blockIdx.y * 128, col0 = blockIdx.x * 64;
    const int kz = blockIdx.z * K;
    const int sr = t >> 2, sq = t & 3;
    const int sqz = sq ^ ((sr >> 1) & 3);
    const int qa = fq ^ ((fr >> 1) & 3);
    const int rbase = w * 32;

    const unsigned short* gA0 = A + (size_t)(row0 + sr) * lda + kz + sq * 8;
    const unsigned short* gA1 = gA0 + (size_t)64 * lda;
    const unsigned short* gB0 = B + (size_t)(col0 + sr) * ldb + kz + sq * 8;

    f32x4 acc[2][4];
#pragma unroll
    for (int i = 0; i < 2; i++)
#pragma unroll
        for (int j = 0; j < 4; j++) acc[i][j] = (f32x4){0.f, 0.f, 0.f, 0.f};

    // prologue: stage K-step 0 (both 32-wide subs) into phase 0
    ushort8 a0 = *(const ushort8*)gA0;
    ushort8 a1 = *(const ushort8*)gA1;
    ushort8 b0 = *(const ushort8*)gB0;
    ushort8 a0b = *(const ushort8*)(gA0 + 32);
    ushort8 a1b = *(const ushort8*)(gA1 + 32);
    ushort8 b0b = *(const ushort8*)(gB0 + 32);
    *(ushort8*)&As[0][0][sr * 32 + sqz * 8] = a0;
    *(ushort8*)&As[0][0][(64 + sr) * 32 + sqz * 8] = a1;
    *(ushort8*)&Bs[0][0][sr * 32 + sqz * 8] = b0;
    *(ushort8*)&As[0][1][sr * 32 + sqz * 8] = a0b;
    *(ushort8*)&As[0][1][(64 + sr) * 32 + sqz * 8] = a1b;
    *(ushort8*)&Bs[0][1][sr * 32 + sqz * 8] = b0b;
    __syncthreads();

    const int nstep = K / 64;                  // 16 (gemm1) / 8 (gemm6) — even
#pragma unroll 1
    for (int p = 0; p < nstep; p += 2) {
#pragma unroll
        for (int h = 0; h < 2; ++h) {          // h = compile-time phase idx
            const int k0 = (p + h) * 64;
            const bool more = (k0 + 64 < K);
            if (more) {                        // 6 next-step loads in flight
                gA0 += 64; gA1 += 64; gB0 += 64;
                a0 = *(const ushort8*)gA0;
                a1 = *(const ushort8*)gA1;
                b0 = *(const ushort8*)gB0;
                a0b = *(const ushort8*)(gA0 + 32);
                a1b = *(const ushort8*)(gA1 + 32);
                b0b = *(const ushort8*)(gB0 + 32);
            }
            bf16x8 af0[2], af1[2], bf0[4], bf1[4];
#pragma unroll
            for (int i = 0; i < 2; i++) {
                ushort8 u0 = *(const ushort8*)&As[h][0][(rbase + i * 16 + fr) * 32 + qa * 8];
                ushort8 u1 = *(const ushort8*)&As[h][1][(rbase + i * 16 + fr) * 32 + qa * 8];
                af0[i] = __builtin_bit_cast(bf16x8, u0);
                af1[i] = __builtin_bit_cast(bf16x8, u1);
            }
#pragma unroll
            for (int j = 0; j < 4; j++) {
                ushort8 u0 = *(const ushort8*)&Bs[h][0][(j * 16 + fr) * 32 + qa * 8];
                ushort8 u1 = *(const ushort8*)&Bs[h][1][(j * 16 + fr) * 32 + qa * 8];
                bf0[j] = __builtin_bit_cast(bf16x8, u0);
                bf1[j] = __builtin_bit_cast(bf16x8, u1);
            }
#pragma unroll
            for (int i = 0; i < 2; i++)
#pragma unroll
                for (int j = 0; j < 4; j++) {
                    acc[i][j] = __builtin_amdgcn_mfma_f32_16x16x32_bf16(
                        af0[i], bf0[j], acc[i][j], 0, 0, 0);
                    acc[i][j] = __builtin_amdgcn_mfma_f32_16x16x32_bf16(
                        af1[i], bf1[j], acc[i][j], 0, 0, 0);
                }
            if (more) {                        // vmcnt wait lands here, post-MFMA
                *(ushort8*)&As[h ^ 1][0][sr * 32 + sqz * 8] = a0;
                *(ushort8*)&As[h ^ 1][0][(64 + sr) * 32 + sqz * 8] = a1;
                *(ushort8*)&Bs[h ^ 1][0][sr * 32 + sqz * 8] = b0;
                *(ushort8*)&As[h ^ 1][1][sr * 32 + sqz * 8] = a0b;
                *(ushort8*)&As[h ^ 1][1][(64 + sr) * 32 + sqz * 8] = a1b;
                *(ushort8*)&Bs[h ^ 1][1][sr * 32 + sqz * 8] = b0b;
                __syncthreads();
            }
        }
    }

#pragma unroll
    for (int i = 0; i < 2; i++) {
#pragma unroll
        for (int r = 0; r < 4; r++) {
            int row = row0 + rbase + i * 16 + fq * 4 + r;
#pragma unroll
            for (int j = 0; j < 4; j++) {
                int col = col0 + j * 16 + fr;
                if (EPI == 0) {
                    float* C = Cbase + (size_t)blockIdx.z * partStride;
                    C[(size_t)row * ldc + col] = acc[i][j][r];
                } else {
                    unsigned short v16 = f2b(acc[i][j][r]);
                    if (col < 2048)
                        ((unsigned short*)Cbase)[(size_t)row * 2048 + col] = v16;
                    else C2[(size_t)row * 2048 + col - 2048] = v16;
                }
            }
        }
    }
}

// ---------------------------------------------------------------------------
// R21: dedicated delta GEMM (gemm4): K=128 whole-K in LDS, ONE barrier.
// Evidence (R19): looped form at 4 K-iters was pure latency (MfmaUtil 0.5%).
__global__ __launch_bounds__(256) void gemm_d4(
    const unsigned short* __restrict__ A,   // bcdB+32, lda=160
    const unsigned short* __restrict__ B,   // wd2_b,  ldb=128
    unsigned short* __restrict__ Cb,        // deltaB (u16), ldc=2048
    const float* __restrict__ bias)
{
    __shared__ unsigned short As[4][128 * 32];
    __shared__ unsigned short Bs[4][64 * 32];
    const int t = threadIdx.x;
    const int w = t >> 6, lane = t & 63;
    const int fr = lane & 15, fq = lane >> 4;
    const int row0 = blockIdx.y * 128, col0 = blockIdx.x * 64;
    const int sr = t >> 2, sq = t & 3;
    const int sqz = sq ^ ((sr >> 1) & 3);
    const int qa = fq ^ ((fr >> 1) & 3);
    const int rbase = w * 32;

    ushort8 a0[4], a1[4], b0[4];
#pragma unroll
    for (int s = 0; s < 4; s++) {
        a0[s] = *(const ushort8*)(A + (size_t)(row0 + sr) * 160 + s * 32 + sq * 8);
        a1[s] = *(const ushort8*)(A + (size_t)(row0 + 64 + sr) * 160 + s * 32 + sq * 8);
        b0[s] = *(const ushort8*)(B + (size_t)(col0 + sr) * 128 + s * 32 + sq * 8);
    }
#pragma unroll
    for (int s = 0; s < 4; s++) {
        *(ushort8*)&As[s][sr * 32 + sqz * 8] = a0[s];
        *(ushort8*)&As[s][(64 + sr) * 32 + sqz * 8] = a1[s];
        *(ushort8*)&Bs[s][sr * 32 + sqz * 8] = b0[s];
    }
    __syncthreads();

    f32x4 acc[2][4];
#pragma unroll
    for (int i = 0; i < 2; i++)
#pragma unroll
        for (int j = 0; j < 4; j++) acc[i][j] = (f32x4){0.f, 0.f, 0.f, 0.f};

#pragma unroll
    for (int s = 0; s < 4; s++) {
        bf16x8 af[2], bfr[4];
#pragma unroll
        for (int i = 0; i < 2; i++) {
            ushort8 u = *(const ushort8*)&As[s][(rbase + i * 16 + fr) * 32 + qa * 8];
            af[i] = __builtin_bit_cast(bf16x8, u);
        }
#pragma unroll
        for (int j = 0; j < 4; j++) {
            ushort8 u = *(const ushort8*)&Bs[s][(j * 16 + fr) * 32 + qa * 8];
            bfr[j] = __builtin_bit_cast(bf16x8, u);
        }
#pragma unroll
        for (int i = 0; i < 2; i++)
#pragma unroll
            for (int j = 0; j < 4; j++)
                acc[i][j] = __builtin_amdgcn_mfma_f32_16x16x32_bf16(
                    af[i], bfr[j], acc[i][j], 0, 0, 0);
    }

#pragma unroll
    for (int i = 0; i < 2; i++) {
#pragma unroll
        for (int r = 0; r < 4; r++) {
            int row = row0 + rbase + i * 16 + fq * 4 + r;
#pragma unroll
            for (int j = 0; j < 4; j++) {
                int col = col0 + j * 16 + fr;
                Cb[(size_t)row * 2048 + col] =
                    f2b(softplusf(bias[col] + acc[i][j][r]));
            }
        }
    }
}

// ---------------------------------------------------------------------------
__global__ __launch_bounds__(256) void bcd_reduce(
    const float* __restrict__ part, unsigned short* __restrict__ bcdB,
    float* __restrict__ bc32)
{
    int t = blockIdx.x * 256 + threadIdx.x;
    if (t >= 327680) return;
    float s = 0.f;
#pragma unroll
    for (int z = 0; z < 8; z++) s += part[(size_t)z * 327680 + t];
    bcdB[t] = f2b(s);
    int col = t % 160;
    if (col < 32) bc32[(size_t)(t / 160) * 32 + col] = s;
}

// sum 4 split-K partials of gemm6 -> final out
__global__ __launch_bounds__(256) void out_reduce(
    const float* __restrict__ part, float* __restrict__ out)
{
    int i = blockIdx.x * 256 + threadIdx.x;    // 524288 float4 groups
    float4 p0 = ((const float4*)part)[i];
    float4 p1 = ((const float4*)(part + 2097152))[i];
    float4 p2 = ((const float4*)(part + 4194304))[i];
    float4 p3 = ((const float4*)(part + 6291456))[i];
    float4 o = {p0.x + p1.x + p2.x + p3.x, p0.y + p1.y + p2.y + p3.y,
                p0.z + p1.z + p2.z + p3.z, p0.w + p1.w + p2.w + p3.w};
    ((float4*)out)[i] = o;
}

// ---------------------------------------------------------------------------
// depthwise causal conv1d (K=4) + bias + SiLU; bf16 in/out, 8 d's per thread.
// R16 (verified): rolling window over 4 consecutive l per thread.
__global__ __launch_bounds__(256) void conv_silu8(
    const unsigned short* __restrict__ aB,
    const float* __restrict__ cw, const float* __restrict__ cb,
    unsigned short* __restrict__ aConvB)
{
    int blk = blockIdx.x;                      // 512 = b*256 + lg
    int lg = blk & 255, b = blk >> 8;
    int l0 = lg << 2;
    int d8 = threadIdx.x << 3;
    const unsigned short* base = aB + (size_t)(b * LSEQ + l0) * 2048 + d8;
    unsigned short* obase = aConvB + (size_t)(b * LSEQ + l0) * 2048 + d8;
    const ushort8 z8 = {0, 0, 0, 0, 0, 0, 0, 0};
    ushort8 xm3, xm2, xm1;
    if (l0 > 0) {                              // l0 multiple of 4 -> l0>=3
        xm3 = *(const ushort8*)(base - 3 * 2048);
        xm2 = *(const ushort8*)(base - 2 * 2048);
        xm1 = *(const ushort8*)(base - 1 * 2048);
    } else { xm3 = z8; xm2 = z8; xm1 = z8; }
    float4 cb0 = *(const float4*)(cb + d8);
    float4 cb1 = *(const float4*)(cb + d8 + 4);
    float bv[8] = {cb0.x, cb0.y, cb0.z, cb0.w, cb1.x, cb1.y, cb1.z, cb1.w};
    float4 w0[8];
#pragma unroll
    for (int j = 0; j < 8; j++) w0[j] = *(const float4*)(cw + (size_t)(d8 + j) * 4);
#pragma unroll
    for (int t = 0; t < 4; t++) {
        ushort8 x0 = *(const ushort8*)(base + t * 2048);
        ushort8 o;
#pragma unroll
        for (int j = 0; j < 8; j++) {
            float acc = bv[j];
            acc = fmaf(b2f(x0[j]),  w0[j].w, acc);
            acc = fmaf(b2f(xm1[j]), w0[j].z, acc);
            acc = fmaf(b2f(xm2[j]), w0[j].y, acc);
            acc = fmaf(b2f(xm3[j]), w0[j].x, acc);
            o[j] = f2b(siluf(acc));
        }
        *(ushort8*)(obase + t * 2048) = o;
        xm3 = xm2; xm2 = xm1; xm1 = x0;
    }
}

// ---------------------------------------------------------------------------
// Chunk-parallel scan, 64 chunks x 16 steps, bf16 inputs (fp32 compute,
// fp32 hend). hend idx(b,c,s,d) = (((b*64+c)*16+s)<<11)+d.
__global__ __launch_bounds__(256) void scan_phaseA(
    const unsigned short* __restrict__ deltaB,
    const unsigned short* __restrict__ aConvB,
    const float* __restrict__ bc32, const float* __restrict__ A_param,
    float* __restrict__ hend, float* __restrict__ Pd)
{
    int blk = blockIdx.x;                      // 1024
    int d = ((blk & 7) << 8) + threadIdx.x;
    int c = (blk >> 3) & 63;
    int b = blk >> 9;
    float expA[16], h[16];
#pragma unroll
    for (int s = 0; s < 16; s++) {
        expA[s] = expf(-A_param[d * 16 + s]);
        h[s] = 0.f;
    }
    float P = 1.f;
    int r0 = b * LSEQ + c * CH;
    const unsigned short* dp = deltaB + (size_t)r0 * D_MODEL + d;
    const unsigned short* ap = aConvB + (size_t)r0 * D_MODEL + d;
    const float4* bp = (const float4*)(bc32 + (size_t)r0 * 32);
    float dlt = b2f(*dp), av = b2f(*ap);
    float4 B0 = bp[0], B1 = bp[1], B2 = bp[2], B3 = bp[3];
    for (int l = 0; l < CH; l++) {
        dp += 2048; ap += 2048; bp += 8;       // prefetch l+1 (lands in ws, safe)
        float nd = b2f(*dp), na = b2f(*ap);
        float4 nB0 = bp[0], nB1 = bp[1], nB2 = bp[2], nB3 = bp[3];
        float Bv[16] = {B0.x, B0.y, B0.z, B0.w, B1.x, B1.y, B1.z, B1.w,
                        B2.x, B2.y, B2.z, B2.w, B3.x, B3.y, B3.z, B3.w};
        float x = dlt * av;
        P *= dlt;
#pragma unroll
        for (int s = 0; s < 16; s++)
            h[s] = fmaf(expA[s] * dlt, h[s], Bv[s] * x);
        dlt = nd; av = na; B0 = nB0; B1 = nB1; B2 = nB2; B3 = nB3;
    }
    size_t base = (((size_t)(b * 64 + c) * 16) << 11) + d;
#pragma unroll
    for (int s = 0; s < 16; s++)
        hend[base + ((size_t)s << 11)] = h[s];
    Pd[(size_t)(b * 64 + c) * 2048 + d] = P;
}

// chunk prefix: overwrite hend[c] with state ENTERING chunk c.
// R16 (verified): depth-4 software prefetch. All register names static.
__global__ __launch_bounds__(256) void scan_phaseB2(
    float* __restrict__ hend, const float* __restrict__ Pd,
    const float* __restrict__ A_param)
{
    int t = blockIdx.x * 256 + threadIdx.x;    // 65536
    int d = t & 2047, s = (t >> 11) & 15, b = t >> 15;
    float e = expf(-A_param[d * 16 + s]);
    float e2 = e * e, e4 = e2 * e2, e8 = e4 * e4;
    float eCH = e8 * e8;                       // expA^16
    size_t idx = (((size_t)(b * 64) * 16 + s) << 11) + d;
    const size_t cs = (size_t)16 << 11;
    size_t pidx = (size_t)(b * 64) * 2048 + d;
    float h = 0.f;
    float he0 = hend[idx], he1 = hend[idx + cs];
    float he2 = hend[idx + 2 * cs], he3 = hend[idx + 3 * cs];
    float P0 = Pd[pidx], P1 = Pd[pidx + 2048];
    float P2 = Pd[pidx + 2 * 2048], P3 = Pd[pidx + 3 * 2048];
    for (int c = 0; c < NCH; c += 4) {
        size_t idx4 = idx + 4 * cs;
        size_t pidx4 = pidx + (size_t)4 * 2048;
        float nh0 = 0.f, nh1 = 0.f, nh2 = 0.f, nh3 = 0.f;
        float nP0 = 0.f, nP1 = 0.f, nP2 = 0.f, nP3 = 0.f;
        if (c + 4 < NCH) {
            nh0 = hend[idx4];          nh1 = hend[idx4 + cs];
            nh2 = hend[idx4 + 2 * cs]; nh3 = hend[idx4 + 3 * cs];
            nP0 = Pd[pidx4];           nP1 = Pd[pidx4 + 2048];
            nP2 = Pd[pidx4 + 2 * 2048]; nP3 = Pd[pidx4 + 3 * 2048];
        }
        hend[idx] = h;            h = fmaf(eCH * P0, h, he0);
        hend[idx + cs] = h;       h = fmaf(eCH * P1, h, he1);
        hend[idx + 2 * cs] = h;   h = fmaf(eCH * P2, h, he2);
        hend[idx + 3 * cs] = h;   h = fmaf(eCH * P3, h, he3);
        idx = idx4; pidx = pidx4;
        he0 = nh0; he1 = nh1; he2 = nh2; he3 = nh3;
        P0 = nP0; P1 = nP1; P2 = nP2; P3 = nP3;
    }
}

__global__ __launch_bounds__(256) void scan_phaseC(
    const unsigned short* __restrict__ deltaB,
    const unsigned short* __restrict__ aConvB,
    const unsigned short* __restrict__ gateB,
    const float* __restrict__ bc32,
    const float* __restrict__ A_param, const float* __restrict__ D_param,
    const float* __restrict__ hend, unsigned short* __restrict__ outB)
{
    int blk = blockIdx.x;                      // 1024
    int d = ((blk & 7) << 8) + threadIdx.x;
    int c = (blk >> 3) & 63;
    int b = blk >> 9;
    float expA[16], h[16];
    size_t base = (((size_t)(b * 64 + c) * 16) << 11) + d;
#pragma unroll
    for (int s = 0; s < 16; s++) {
        expA[s] = expf(-A_param[d * 16 + s]);
        h[s] = hend[base + ((size_t)s << 11)];
    }
    float Dp = D_param[d];
    int r0 = b * LSEQ + c * CH;
    const unsigned short* dp = deltaB + (size_t)r0 * D_MODEL + d;
    const unsigned short* ap = aConvB + (size_t)r0 * D_MODEL + d;
    const unsigned short* gp = gateB + (size_t)r0 * 2048 + d;
    const float4* bp = (const float4*)(bc32 + (size_t)r0 * 32);
    unsigned short* op = outB + (size_t)r0 * D_MODEL + d;
    float dlt = b2f(*dp), av = b2f(*ap), g = b2f(*gp);
    float4 B0 = bp[0], B1 = bp[1], B2 = bp[2], B3 = bp[3];
    float4 C0 = bp[4], C1 = bp[5], C2 = bp[6], C3 = bp[7];
    for (int l = 0; l < CH; l++) {
        dp += 2048; ap += 2048; gp += 2048; bp += 8;
        float nd = b2f(*dp), na = b2f(*ap), ng = b2f(*gp);
        float4 nB0 = bp[0], nB1 = bp[1], nB2 = bp[2], nB3 = bp[3];
        float4 nC0 = bp[4], nC1 = bp[5], nC2 = bp[6], nC3 = bp[7];
        float Bv[16] = {B0.x, B0.y, B0.z, B0.w, B1.x, B1.y, B1.z, B1.w,
                        B2.x, B2.y, B2.z, B2.w, B3.x, B3.y, B3.z, B3.w};
        float Cv[16] = {C0.x, C0.y, C0.z, C0.w, C1.x, C1.y, C1.z, C1.w,
                        C2.x, C2.y, C2.z, C2.w, C3.x, C3.y, C3.z, C3.w};
        float x = dlt * av;
        float acc = 0.f;
#pragma unroll
        for (int s = 0; s < 16; s++) {
            float Ab = expA[s] * dlt;
            h[s] = fmaf(Ab, h[s], Bv[s] * x);
            acc = fmaf(h[s], Cv[s], acc);
        }
        *op = f2b((acc + Dp * av) * siluf(g));
        op += D_MODEL;
        dlt = nd; av = na; g = ng;
        B0 = nB0; B1 = nB1; B2 = nB2; B3 = nB3;
        C0 = nC0; C1 = nC1; C2 = nC2; C3 = nC3;
    }
}

extern "C" void kernel_launch(void* const* d_in, const int* in_sizes, int n_in,
                              void* d_out, int out_size, void* d_ws, size_t ws_size,
                              hipStream_t stream) {
    const float* seq = (const float*)d_in[0];
    const float* w_in = (const float*)d_in[1];
    const float* w_out = (const float*)d_in[2];
    const float* w_B = (const float*)d_in[3];
    const float* w_C = (const float*)d_in[4];
    const float* w_D1 = (const float*)d_in[5];
    const float* w_D2 = (const float*)d_in[6];
    const float* conv_w = (const float*)d_in[7];
    const float* conv_b = (const float*)d_in[8];
    const float* A_param = (const float*)d_in[9];
    const float* D_param = (const float*)d_in[10];
    float* out = (float*)d_out;

    // fp32 region (floats)
    float* bc32  = (float*)d_ws;                   // 65,536
    float* part  = bc32 + (size_t)65536;           // 2,621,440 (dead after reduce)
    float* part6 = part + (size_t)2621440;         // 8,388,608 (gemm6 partials)
    float* Pd    = part;                           // overlay: 262,144 ✓ (part dead)
    float* hend  = part6;                          // overlay: 4,194,304 ✓ (hend dead
                                                   //  before gemm6 writes part6)
    // bf16 region
    unsigned short* seq_b  = (unsigned short*)(part6 + 8388608);
    unsigned short* win_b  = seq_b + (size_t)2097152;
    unsigned short* wout_b = win_b + (size_t)4194304;
    unsigned short* wbcd_b = wout_b + (size_t)2097152;  // [160,2048]
    unsigned short* wd2_b  = wbcd_b + (size_t)327680;   // [2048,128]
    unsigned short* aB     = wd2_b + (size_t)262144;    // [2048,2048]
    unsigned short* aConvB = aB + (size_t)4194304;      // [2048,2048]
    unsigned short* deltaB = aConvB + (size_t)4194304;  // [2048,2048]
    unsigned short* gateB  = deltaB + (size_t)4194304;  // [2048,2048]
    unsigned short* outB   = gateB + (size_t)4194304;   // [2048,2048]
    unsigned short* bcdB   = outB + (size_t)4194304;    // [2048,160]

    // 0) casts
    cast_all<<<dim3(4384), 256, 0, stream>>>(seq, w_in, w_out, w_B, w_C, w_D1, w_D2,
                                             seq_b, win_b, wout_b, wbcd_b, wd2_b);
    // 1) [a|gate] = seq @ w_in^T  [2048 x 4096] K=1024; BK=64 (R22)
    gemm_bk64<5><<<dim3(64, 16), 256, 0, stream>>>(seq_b, 1024, win_b, 1024,
                                                   (float*)aB, 2048, 0, 1024, gateB);
    // 2) conv + SiLU (bf16 in/out, 8-wide, 4-l rolling window)
    conv_silu8<<<dim3(512), 256, 0, stream>>>(aB, conv_w, conv_b, aConvB);
    // 3) bcd split-K x8, TN=64, K=256/block -> short-K, runtime-buf loop
    gemm_db<64, false><<<dim3(3, 16, 8), 256, 0, stream>>>(aConvB, 2048, wbcd_b, 2048,
                                                    part, 160, 327680, 160, 256,
                                                    nullptr, nullptr, 0);
    bcd_reduce<<<dim3(1280), 256, 0, stream>>>(part, bcdB, bc32);
    // 4) deltaB = bf16(softplus(D + d1 @ wD2^T))  K=128 -> R21 whole-K kernel
    gemm_d4<<<dim3(32, 16), 256, 0, stream>>>(bcdB + 32, wd2_b,
                                              deltaB, D_param);
    // 5) chunk-parallel scan (64 chunks x 16 steps; bf16 datapath, fp32 hend)
    scan_phaseA<<<dim3(1024), 256, 0, stream>>>(deltaB, aConvB, bc32, A_param,
                                                hend, Pd);
    scan_phaseB2<<<dim3(256), 256, 0, stream>>>(hend, Pd, A_param);
    scan_phaseC<<<dim3(1024), 256, 0, stream>>>(deltaB, aConvB, gateB, bc32,
                                                A_param, D_param, hend, outB);
    // 6) out = ssm_out @ w_out^T  K=512/block, split-K x4; R23: BK=64
    gemm_bk64<0><<<dim3(16, 16, 4), 256, 0, stream>>>(outB, 2048, wout_b, 2048,
                                                      part6, 1024, 2097152, 512,
                                                      nullptr);
    out_reduce<<<dim3(2048), 256, 0, stream>>>(part6, out);
}